// Round 3
// baseline (1963.236 us; speedup 1.0000x reference)
//
#include <hip/hip_runtime.h>

// ERNN cell on MI355X. Inputs/outputs FLOAT32. Output f32.
// Math: P = V2@V + I;  wxp[t] = x[t]@(W@P) + b@P  (parallel precompute, bf16)
//   per step: s = h_cur + h_prev;  pre = s + s@(P^2 - I) + wxp[t]
//   h_cur = a*(tanh(pre) - h_prev) + (1-a)*h_cur   (K iters, K=1)
// Identity split keeps MFMA operand E = P^2 - I small -> bf16 rounding harmless.
//
// R7 changes (latency-filling theory):
//  - R4/R5/R6 all land at ~2000 cy/step despite wildly different LDS/VALU mixes
//    => the step is dominated by a fixed latency chain (write->barrier->ds_read
//    ->MFMA chain->tanh chain), with pipes ~70% idle.
//  - Fix: each WG now owns TWO independent 16-row batch panels (32 rows, 8 WGs).
//    Panels share Ef registers + the barrier, but their ds_reads / 8 interleaved
//    MFMA chains / epilogues are independent ILP -> latency paid once for 2x work.
//  - Everything else (swizzled S, raw barrier + lgkmcnt-only drain, 1-step wx
//    prefetch, K==1 q-form) carried from R6.

#define HID   256
#define NF    128
#define SEQ   1024
#define SSTR  264    // s LDS row stride in bf16 elems (pad 8; keeps rows 16B-aligned)
#define PLB   (16 * SSTR * 2)   // bytes per 16-row S plane (8448)

typedef __bf16 bf16_t;
typedef __bf16 bf16x8 __attribute__((ext_vector_type(8)));
typedef float  f32x4  __attribute__((ext_vector_type(4)));

__device__ __forceinline__ float fast_tanh(float x) {
    float e = __builtin_amdgcn_exp2f(x * 2.8853900817779268f);
    return 1.0f - 2.0f * __builtin_amdgcn_rcpf(e + 1.0f);
}

// swizzle bit: byte ^= parity(row>>2)<<5 (spreads the 4 quads' write banks)
__device__ __forceinline__ int s_swz(int row) {
    return (((row >> 2) ^ (row >> 3)) & 1) << 5;
}

// ---------- k0: P = V2@V + I (f32) ----------
__global__ void k_P(const float* __restrict__ V2, const float* __restrict__ V,
                    float* __restrict__ P) {
    __shared__ float v2row[64];
    int i = blockIdx.x, j = threadIdx.x;
    if (j < 64) v2row[j] = V2[i * 64 + j];
    __syncthreads();
    float s = (i == j) ? 1.0f : 0.0f;
    #pragma unroll 4
    for (int v = 0; v < 64; ++v) s += v2row[v] * V[v * HID + j];
    P[i * HID + j] = s;
}

// ---------- k1: Et = bf16((P@P - I)^T) ----------
__global__ void k_E(const float* __restrict__ P, bf16_t* __restrict__ Et) {
    __shared__ float prow[HID];
    int i = blockIdx.x, j = threadIdx.x;
    prow[j] = P[i * HID + j];
    __syncthreads();
    float s = (i == j) ? -1.0f : 0.0f;
    #pragma unroll 4
    for (int k = 0; k < HID; ++k) s += prow[k] * P[k * HID + j];
    Et[(size_t)j * HID + i] = (bf16_t)s;   // Et[col][k] = E[k][col]
}

// ---------- k2: WPt = bf16((W@P)^T), bP = b@P (f32) ----------
__global__ void k_WP(const float* __restrict__ W, const float* __restrict__ b,
                     const float* __restrict__ P,
                     bf16_t* __restrict__ WPt, float* __restrict__ bP) {
    __shared__ float row[HID];
    int i = blockIdx.x, j = threadIdx.x;
    if (i < NF) {
        row[j] = W[i * HID + j];
        __syncthreads();
        float s = 0.f;
        #pragma unroll 4
        for (int k = 0; k < HID; ++k) s += row[k] * P[k * HID + j];
        WPt[(size_t)j * NF + i] = (bf16_t)s;
    } else {
        row[j] = b[j];
        __syncthreads();
        float s = 0.f;
        #pragma unroll 4
        for (int k = 0; k < HID; ++k) s += row[k] * P[k * HID + j];
        bP[j] = s;
    }
}

// ---------- k3: wxp = bf16(x@WP + bP) in 16-row-tile scan-ready layout ----------
// tile = t*16 + g16 (g16 = 16-row batch group). Scan thread tid reads bf16x8 at
//   tile*4096 + tid*8  and  tile*4096 + 2048 + tid*8.
__global__ __launch_bounds__(256) void k_wxp(const float* __restrict__ x,
                                             const bf16_t* __restrict__ WPt,
                                             const float* __restrict__ bP,
                                             bf16_t* __restrict__ wxp) {
    int tid = threadIdx.x;
    int lane = tid & 63, w = tid >> 6;
    int quad = lane >> 4, m = lane & 15;
    bf16x8 Bf[4][4];
    float bPv[4];
    #pragma unroll
    for (int c = 0; c < 4; ++c) {
        int col = w * 64 + c * 16 + m;
        bPv[c] = bP[col];
        const bf16_t* wp = WPt + (size_t)col * NF + quad * 8;
        #pragma unroll
        for (int kt = 0; kt < 4; ++kt)
            Bf[c][kt] = *(const bf16x8*)(wp + kt * 32);
    }
    for (int i = 0; i < 8; ++i) {
        int tile = blockIdx.x * 8 + i;          // t*16 + g16
        int t = tile >> 4, g = tile & 15;
        const float* xp = x + (((size_t)t * 256 + g * 16 + m) * NF + quad * 8);
        f32x4 acc[4];
        #pragma unroll
        for (int c = 0; c < 4; ++c) acc[c] = (f32x4){bPv[c], bPv[c], bPv[c], bPv[c]};
        #pragma unroll
        for (int kt = 0; kt < 4; ++kt) {
            f32x4 xa = *(const f32x4*)(xp + kt * 32);
            f32x4 xb = *(const f32x4*)(xp + kt * 32 + 4);
            bf16x8 aa;
            #pragma unroll
            for (int j = 0; j < 4; ++j) { aa[j] = (bf16_t)xa[j]; aa[4 + j] = (bf16_t)xb[j]; }
            #pragma unroll
            for (int c = 0; c < 4; ++c)
                acc[c] = __builtin_amdgcn_mfma_f32_16x16x32_bf16(aa, Bf[c][kt], acc[c], 0, 0, 0);
        }
        bf16x8 lo, hi;
        #pragma unroll
        for (int c = 0; c < 2; ++c)
            #pragma unroll
            for (int r = 0; r < 4; ++r) {
                lo[c * 4 + r] = (bf16_t)acc[c][r];
                hi[c * 4 + r] = (bf16_t)acc[2 + c][r];
            }
        size_t tb = (size_t)tile * 4096;
        *(bf16x8*)(wxp + tb + tid * 8)        = lo;
        *(bf16x8*)(wxp + tb + 2048 + tid * 8) = hi;
    }
}

// ---------- k4: scan, 8 WGs x 256 threads, 2 independent 16-row panels per WG ----------
__global__ __launch_bounds__(256, 1) void k_scan_pre(const float* __restrict__ h_in,
                                                     const float* __restrict__ alpha,
                                                     const int* __restrict__ Kp,
                                                     const bf16_t* __restrict__ Et,
                                                     const bf16_t* __restrict__ wxp,
                                                     float* __restrict__ out) {
    // S planes: [buf 2][panel 2][16 x SSTR]
    __shared__ bf16_t S[2 * 2 * 16 * SSTR];
    int g = blockIdx.x;                    // 0..7 -> panels g*2, g*2+1
    int tid = threadIdx.x;
    int lane = tid & 63, w = tid >> 6, quad = lane >> 4, m = lane & 15;
    int colbase = w * 64 + m;

    // B fragments of E for this wave's 64 cols (4 col-tiles x 8 k-tiles), shared by panels
    bf16x8 Ef[32];
    #pragma unroll
    for (int c = 0; c < 4; ++c) {
        const bf16_t* ep = Et + (size_t)(colbase + c * 16) * HID + quad * 8;
        #pragma unroll
        for (int kt = 0; kt < 8; ++kt)
            Ef[c * 8 + kt] = *(const bf16x8*)(ep + kt * 32);
    }

    const int rd_base = (m * (SSTR * 2) + quad * 16) ^ s_swz(m);
    int woff[16];
    #pragma unroll
    for (int c = 0; c < 4; ++c)
        #pragma unroll
        for (int r = 0; r < 4; ++r) {
            int row = quad * 4 + r, col = colbase + c * 16;
            woff[c * 4 + r] = ((row * SSTR + col) * 2) ^ s_swz(row);
        }

    float a = alpha[0];
    int K = Kp[0];
    if (K < 1 || K > 64) K = 1;

    char* const sbase = (char*)&S[0];

    // load h for both panels; init S buf0
    float q[32];
    #pragma unroll
    for (int pi = 0; pi < 2; ++pi)
        #pragma unroll
        for (int c = 0; c < 4; ++c)
            #pragma unroll
            for (int r = 0; r < 4; ++r) {
                int e = c * 4 + r;
                int row = quad * 4 + r, col = colbase + c * 16;
                float v = h_in[((g * 2 + pi) * 16 + row) * HID + col];
                q[pi * 16 + e] = 2.0f * v;
                *(bf16_t*)(sbase + pi * PLB + woff[e]) = (bf16_t)(2.0f * v);
            }
    __syncthreads();

    const bf16_t* wlo0 = wxp + (size_t)(g * 2 + 0) * 4096 + (size_t)tid * 8;
    const bf16_t* wlo1 = wxp + (size_t)(g * 2 + 1) * 4096 + (size_t)tid * 8;
    const long WSTR = 65536;   // elems per timestep (16 tiles * 4096)

    if (K == 1) {
        // K==1: hp==hc -> single state q = 2*h;
        // q' = 2a*tanh(pre) + (1-2a)*q, pre = acc + q, h_out = q/2.
        const float A2 = 2.0f * a, B2 = 1.0f - 2.0f * a;

        bf16x8 c0l = *(const bf16x8*)(wlo0);
        bf16x8 c0h = *(const bf16x8*)(wlo0 + 2048);
        bf16x8 c1l = *(const bf16x8*)(wlo1);
        bf16x8 c1h = *(const bf16x8*)(wlo1 + 2048);

        auto step = [&](int P, int t) {   // P literal at both call sites
            int tn = (t + 1 < SEQ) ? t + 1 : t;
            // next-step wx prefetch (stays in flight across the barrier)
            bf16x8 n0l = *(const bf16x8*)(wlo0 + (long)tn * WSTR);
            bf16x8 n0h = *(const bf16x8*)(wlo0 + (long)tn * WSTR + 2048);
            bf16x8 n1l = *(const bf16x8*)(wlo1 + (long)tn * WSTR);
            bf16x8 n1h = *(const bf16x8*)(wlo1 + (long)tn * WSTR + 2048);

            f32x4 acc0[4], acc1[4];
            #pragma unroll
            for (int r = 0; r < 4; ++r) {
                acc0[0][r] = (float)c0l[r];  acc0[1][r] = (float)c0l[4 + r];
                acc0[2][r] = (float)c0h[r];  acc0[3][r] = (float)c0h[4 + r];
                acc1[0][r] = (float)c1l[r];  acc1[1][r] = (float)c1l[4 + r];
                acc1[2][r] = (float)c1h[r];  acc1[3][r] = (float)c1h[4 + r];
            }
            const char* sb0 = sbase + P * (2 * PLB);
            const char* sb1 = sb0 + PLB;
            // 8 interleaved MFMA chains (4 per panel) -> dep latency fully covered
            #pragma unroll
            for (int kt = 0; kt < 8; ++kt) {
                bf16x8 a0 = *(const bf16x8*)(sb0 + rd_base + kt * 64);
                bf16x8 a1 = *(const bf16x8*)(sb1 + rd_base + kt * 64);
                #pragma unroll
                for (int c = 0; c < 4; ++c)
                    acc0[c] = __builtin_amdgcn_mfma_f32_16x16x32_bf16(a0, Ef[c * 8 + kt], acc0[c], 0, 0, 0);
                #pragma unroll
                for (int c = 0; c < 4; ++c)
                    acc1[c] = __builtin_amdgcn_mfma_f32_16x16x32_bf16(a1, Ef[c * 8 + kt], acc1[c], 0, 0, 0);
            }
            char* sw0 = sbase + (P ^ 1) * (2 * PLB);
            char* sw1 = sw0 + PLB;
            #pragma unroll
            for (int c = 0; c < 4; ++c)
                #pragma unroll
                for (int r = 0; r < 4; ++r) {
                    int e = c * 4 + r;
                    float pre = acc0[c][r] + q[e];
                    float T = fast_tanh(pre);
                    float qn = fmaf(A2, T, B2 * q[e]);
                    q[e] = qn;
                    *(bf16_t*)(sw0 + woff[e]) = (bf16_t)qn;
                }
            #pragma unroll
            for (int c = 0; c < 4; ++c)
                #pragma unroll
                for (int r = 0; r < 4; ++r) {
                    int e = c * 4 + r;
                    float pre = acc1[c][r] + q[16 + e];
                    float T = fast_tanh(pre);
                    float qn = fmaf(A2, T, B2 * q[16 + e]);
                    q[16 + e] = qn;
                    *(bf16_t*)(sw1 + woff[e]) = (bf16_t)qn;
                }
            // drain LDS only; global prefetches remain in flight
            asm volatile("s_waitcnt lgkmcnt(0)" ::: "memory");
            __builtin_amdgcn_s_barrier();
            __builtin_amdgcn_sched_barrier(0);
            c0l = n0l; c0h = n0h; c1l = n1l; c1h = n1h;
        };
        for (int t = 0; t < SEQ; t += 2) { step(0, t); step(1, t + 1); }

        #pragma unroll
        for (int pi = 0; pi < 2; ++pi)
            #pragma unroll
            for (int c = 0; c < 4; ++c)
                #pragma unroll
                for (int r = 0; r < 4; ++r) {
                    int row = quad * 4 + r, col = colbase + c * 16;
                    out[((g * 2 + pi) * 16 + row) * HID + col] = 0.5f * q[pi * 16 + c * 4 + r];
                }
    } else {
        // general K path (not exercised by the bench; kept correct, may spill)
        float hp[32], hc[32], sreg[32];
        #pragma unroll
        for (int e = 0; e < 32; ++e) { hp[e] = 0.5f * q[e]; hc[e] = hp[e]; sreg[e] = q[e]; }
        float one_ma = 1.0f - a;
        bf16x8 c0l = *(const bf16x8*)(wlo0);
        bf16x8 c0h = *(const bf16x8*)(wlo0 + 2048);
        bf16x8 c1l = *(const bf16x8*)(wlo1);
        bf16x8 c1h = *(const bf16x8*)(wlo1 + 2048);
        int p = 0;
        for (int t = 0; t < SEQ; ++t) {
            int tn = (t + 1 < SEQ) ? t + 1 : t;
            bf16x8 n0l = *(const bf16x8*)(wlo0 + (long)tn * WSTR);
            bf16x8 n0h = *(const bf16x8*)(wlo0 + (long)tn * WSTR + 2048);
            bf16x8 n1l = *(const bf16x8*)(wlo1 + (long)tn * WSTR);
            bf16x8 n1h = *(const bf16x8*)(wlo1 + (long)tn * WSTR + 2048);
            for (int k = 0; k < K; ++k) {
                f32x4 acc0[4], acc1[4];
                #pragma unroll
                for (int r = 0; r < 4; ++r) {
                    acc0[0][r] = (float)c0l[r];  acc0[1][r] = (float)c0l[4 + r];
                    acc0[2][r] = (float)c0h[r];  acc0[3][r] = (float)c0h[4 + r];
                    acc1[0][r] = (float)c1l[r];  acc1[1][r] = (float)c1l[4 + r];
                    acc1[2][r] = (float)c1h[r];  acc1[3][r] = (float)c1h[4 + r];
                }
                const char* sb0 = sbase + p * (2 * PLB);
                const char* sb1 = sb0 + PLB;
                #pragma unroll
                for (int kt = 0; kt < 8; ++kt) {
                    bf16x8 a0 = *(const bf16x8*)(sb0 + rd_base + kt * 64);
                    bf16x8 a1 = *(const bf16x8*)(sb1 + rd_base + kt * 64);
                    #pragma unroll
                    for (int c = 0; c < 4; ++c)
                        acc0[c] = __builtin_amdgcn_mfma_f32_16x16x32_bf16(a0, Ef[c * 8 + kt], acc0[c], 0, 0, 0);
                    #pragma unroll
                    for (int c = 0; c < 4; ++c)
                        acc1[c] = __builtin_amdgcn_mfma_f32_16x16x32_bf16(a1, Ef[c * 8 + kt], acc1[c], 0, 0, 0);
                }
                bool last = (k == K - 1);
                char* sw0 = sbase + (p ^ 1) * (2 * PLB);
                char* sw1 = sw0 + PLB;
                #pragma unroll
                for (int pi = 0; pi < 2; ++pi) {
                    char* sw = pi ? sw1 : sw0;
                    #pragma unroll
                    for (int c = 0; c < 4; ++c)
                        #pragma unroll
                        for (int r = 0; r < 4; ++r) {
                            int e = c * 4 + r;
                            int ee = pi * 16 + e;
                            f32x4* acc = pi ? acc1 : acc0;
                            float pre = acc[c][r] + sreg[ee];
                            float T = fast_tanh(pre);
                            float hn = a * (T - hp[ee]) + one_ma * hc[ee];
                            float sn;
                            if (last) { hp[ee] = hn; hc[ee] = hn; sn = 2.0f * hn; }
                            else      { hc[ee] = hn; sn = hn + hp[ee]; }
                            sreg[ee] = sn;
                            *(bf16_t*)(sw + woff[e]) = (bf16_t)sn;
                        }
                }
                p ^= 1;
                __syncthreads();
            }
            c0l = n0l; c0h = n0h; c1l = n1l; c1h = n1h;
        }
        #pragma unroll
        for (int pi = 0; pi < 2; ++pi)
            #pragma unroll
            for (int c = 0; c < 4; ++c)
                #pragma unroll
                for (int r = 0; r < 4; ++r) {
                    int row = quad * 4 + r, col = colbase + c * 16;
                    out[((g * 2 + pi) * 16 + row) * HID + col] = hp[pi * 16 + c * 4 + r];
                }
    }
}

// ---------- fallback: fused scan (16 WGs x 256 threads), wxp workspace unavailable ----------
__global__ __launch_bounds__(256, 1) void k_scan_fused(const float* __restrict__ h_in,
                                                 const float* __restrict__ alpha,
                                                 const int* __restrict__ Kp,
                                                 const bf16_t* __restrict__ Et,
                                                 const bf16_t* __restrict__ WPt,
                                                 const float* __restrict__ bP,
                                                 const float* __restrict__ x,
                                                 float* __restrict__ out) {
    __shared__ bf16_t S[2][16 * SSTR];
    int g = blockIdx.x;
    int tid = threadIdx.x;
    int lane = tid & 63, w = tid >> 6, quad = lane >> 4, m = lane & 15;
    int colbase = w * 64 + m;
    bf16x8 Ef[32];
    bf16x8 Wf[16];
    float bPv[4];
    #pragma unroll
    for (int c = 0; c < 4; ++c) {
        int col = colbase + c * 16;
        bPv[c] = bP[col];
        const bf16_t* ep = Et + (size_t)col * HID + quad * 8;
        #pragma unroll
        for (int kt = 0; kt < 8; ++kt)
            Ef[c * 8 + kt] = *(const bf16x8*)(ep + kt * 32);
        const bf16_t* wpp = WPt + (size_t)col * NF + quad * 8;
        #pragma unroll
        for (int kt = 0; kt < 4; ++kt)
            Wf[c * 4 + kt] = *(const bf16x8*)(wpp + kt * 32);
    }
    float hp[16], hc[16], sreg[16];
    #pragma unroll
    for (int c = 0; c < 4; ++c)
        #pragma unroll
        for (int r = 0; r < 4; ++r) {
            int e = c * 4 + r;
            int row = quad * 4 + r, col = colbase + c * 16;
            float v = h_in[(g * 16 + row) * HID + col];
            hp[e] = v; hc[e] = v; sreg[e] = 2.0f * v;
            S[0][row * SSTR + col] = (bf16_t)(2.0f * v);
        }
    float a = alpha[0];
    float one_ma = 1.0f - a;
    int K = Kp[0];
    if (K < 1 || K > 64) K = 1;
    __syncthreads();
    const float* xrow = x + ((g * 16 + m) * NF + quad * 8);
    bf16x8 xf[4];
    #pragma unroll
    for (int kt = 0; kt < 4; ++kt) {
        f32x4 xa = *(const f32x4*)(xrow + kt * 32);
        f32x4 xb = *(const f32x4*)(xrow + kt * 32 + 4);
        bf16x8 f;
        #pragma unroll
        for (int j = 0; j < 4; ++j) { f[j] = (bf16_t)xa[j]; f[4 + j] = (bf16_t)xb[j]; }
        xf[kt] = f;
    }
    int p = 0;
    for (int t = 0; t < SEQ; ++t) {
        int tn = (t + 1 < SEQ) ? t + 1 : t;
        const float* xn = xrow + (size_t)tn * (256 * NF);
        bf16x8 xnf[4];
        #pragma unroll
        for (int kt = 0; kt < 4; ++kt) {
            f32x4 xa = *(const f32x4*)(xn + kt * 32);
            f32x4 xb = *(const f32x4*)(xn + kt * 32 + 4);
            bf16x8 f;
            #pragma unroll
            for (int j = 0; j < 4; ++j) { f[j] = (bf16_t)xa[j]; f[4 + j] = (bf16_t)xb[j]; }
            xnf[kt] = f;
        }
        f32x4 wxacc[4];
        #pragma unroll
        for (int c = 0; c < 4; ++c) wxacc[c] = (f32x4){bPv[c], bPv[c], bPv[c], bPv[c]};
        #pragma unroll
        for (int kt = 0; kt < 4; ++kt)
            #pragma unroll
            for (int c = 0; c < 4; ++c)
                wxacc[c] = __builtin_amdgcn_mfma_f32_16x16x32_bf16(xf[kt], Wf[c * 4 + kt], wxacc[c], 0, 0, 0);
        for (int k = 0; k < K; ++k) {
            f32x4 acc[4];
            #pragma unroll
            for (int c = 0; c < 4; ++c) acc[c] = wxacc[c];
            const bf16_t* sbase = &S[p][m * SSTR];
            #pragma unroll
            for (int kt = 0; kt < 8; ++kt) {
                bf16x8 af = *(const bf16x8*)(sbase + kt * 32 + quad * 8);
                #pragma unroll
                for (int c = 0; c < 4; ++c)
                    acc[c] = __builtin_amdgcn_mfma_f32_16x16x32_bf16(af, Ef[c * 8 + kt], acc[c], 0, 0, 0);
            }
            bool last = (k == K - 1);
            #pragma unroll
            for (int c = 0; c < 4; ++c) {
                int col = colbase + c * 16;
                #pragma unroll
                for (int r = 0; r < 4; ++r) {
                    int e = c * 4 + r;
                    int row = quad * 4 + r;
                    float pre = acc[c][r] + sreg[e];
                    float T = fast_tanh(pre);
                    float hn = a * (T - hp[e]) + one_ma * hc[e];
                    float sn;
                    if (last) { hp[e] = hn; hc[e] = hn; sn = 2.0f * hn; }
                    else      { hc[e] = hn; sn = hn + hp[e]; }
                    sreg[e] = sn;
                    S[p ^ 1][row * SSTR + col] = (bf16_t)sn;
                }
            }
            p ^= 1;
            __syncthreads();
        }
        #pragma unroll
        for (int kt = 0; kt < 4; ++kt) xf[kt] = xnf[kt];
    }
    #pragma unroll
    for (int c = 0; c < 4; ++c)
        #pragma unroll
        for (int r = 0; r < 4; ++r) {
            int row = quad * 4 + r, col = colbase + c * 16;
            out[(g * 16 + row) * HID + col] = hp[c * 4 + r];
        }
}

extern "C" void kernel_launch(void* const* d_in, const int* in_sizes, int n_in,
                              void* d_out, int out_size, void* d_ws, size_t ws_size,
                              hipStream_t stream) {
    const float* x     = (const float*)d_in[0];
    const float* h     = (const float*)d_in[1];
    const float* W     = (const float*)d_in[2];
    const float* b     = (const float*)d_in[3];
    const float* V     = (const float*)d_in[4];
    const float* V2    = (const float*)d_in[5];
    const float* alpha = (const float*)d_in[6];
    const int*   Kp    = (const int*)d_in[7];

    char* ws = (char*)d_ws;
    float*  P   = (float*)ws;                     // 256 KB
    bf16_t* Et  = (bf16_t*)(ws + (256u << 10));   // 128 KB (E^T)
    bf16_t* WPt = (bf16_t*)(ws + (384u << 10));   // 64 KB ((W@P)^T)
    float*  bP  = (float*)(ws + (448u << 10));    // 1 KB
    bf16_t* wxp = (bf16_t*)(ws + (512u << 10));   // 128 MB (optional)
    size_t need = (512u << 10) + (size_t)SEQ * 16 * 512 * 8 * sizeof(bf16_t);

    hipLaunchKernelGGL(k_P,  dim3(256), dim3(256), 0, stream, V2, V, P);
    hipLaunchKernelGGL(k_E,  dim3(256), dim3(256), 0, stream, P, Et);
    hipLaunchKernelGGL(k_WP, dim3(129), dim3(256), 0, stream, W, b, P, WPt, bP);
    if (ws_size >= need) {
        hipLaunchKernelGGL(k_wxp, dim3(2048), dim3(256), 0, stream, x, WPt, bP, wxp);
        hipLaunchKernelGGL(k_scan_pre, dim3(8), dim3(256), 0, stream, h, alpha, Kp, Et, wxp, (float*)d_out);
    } else {
        hipLaunchKernelGGL(k_scan_fused, dim3(16), dim3(256), 0, stream, h, alpha, Kp, Et, WPt, bP, x, (float*)d_out);
    }
}

// Round 4
// 1123.983 us; speedup vs baseline: 1.7467x; 1.7467x over previous
//
#include <hip/hip_runtime.h>

// ERNN cell on MI355X. Inputs/outputs FLOAT32. Output f32.
// Math: P = V2@V + I;  wxp[t] = x[t]@(W@P) + b@P  (parallel precompute, bf16)
//   per step: s = h_cur + h_prev;  pre = s + s@(P^2 - I) + wxp[t]
//   h_cur = a*(tanh(pre) - h_prev) + (1-a)*h_cur   (K iters, K=1)
// Identity split keeps MFMA operand E = P^2 - I small -> bf16 rounding harmless.
//
// R8 changes (issue-bound theory):
//  - R7 (2 panels/WG) ran exactly 2x slower per step => per-SIMD issue-bound,
//    not latency-bound. Revert to R6 structure (16 WGs x 256 thr, proven 836us)
//    and diet the epilogue instruction stream instead:
//  - LAMBDA-prescaling: wxp, S, q all carry lambda = 2*log2(e). exp2 consumes
//    pre directly (the per-element tanh mul disappears; all paths are linear).
//  - qn = fma(-2A, u, fma(B2, q, A)) with u = rcp(exp2(pre)+1) -- 2 FMA, no T.
//  - f32x2 row-pair epilogue -> v_pk_add_f32 / v_pk_fma_f32 (FP contraction on).
//  - Carried from R6: S XOR-swizzle, raw s_barrier + lgkmcnt-only drain
//    (global prefetches stay in flight), 2-deep wx prefetch, split MFMA chains.

#define HID   256
#define NF    128
#define SEQ   1024
#define SSTR  264    // s LDS row stride in bf16 elems (pad 8; keeps rows 16B-aligned)
#define LAM   2.8853900817779268f   // 2*log2(e)

typedef __bf16 bf16_t;
typedef __bf16 bf16x8 __attribute__((ext_vector_type(8)));
typedef float  f32x4  __attribute__((ext_vector_type(4)));
typedef float  f32x2  __attribute__((ext_vector_type(2)));

__device__ __forceinline__ float fast_tanh_scaled(float pre_l) {
    // pre_l = LAM * pre;  tanh(pre) = 1 - 2/(exp2(pre_l)+1)
    float e = __builtin_amdgcn_exp2f(pre_l);
    return 1.0f - 2.0f * __builtin_amdgcn_rcpf(e + 1.0f);
}

// physical byte offset of S element (row,col) = ((row*SSTR+col)*2) ^ (parity(row>>2)<<5)
__device__ __forceinline__ int s_swz(int row) {
    return (((row >> 2) ^ (row >> 3)) & 1) << 5;
}

// ---------- k0: P = V2@V + I (f32) ----------
__global__ void k_P(const float* __restrict__ V2, const float* __restrict__ V,
                    float* __restrict__ P) {
    __shared__ float v2row[64];
    int i = blockIdx.x, j = threadIdx.x;
    if (j < 64) v2row[j] = V2[i * 64 + j];
    __syncthreads();
    float s = (i == j) ? 1.0f : 0.0f;
    #pragma unroll 4
    for (int v = 0; v < 64; ++v) s += v2row[v] * V[v * HID + j];
    P[i * HID + j] = s;
}

// ---------- k1: Et = bf16((P@P - I)^T)  (transposed -> vector B-frag loads) ----------
__global__ void k_E(const float* __restrict__ P, bf16_t* __restrict__ Et) {
    __shared__ float prow[HID];
    int i = blockIdx.x, j = threadIdx.x;
    prow[j] = P[i * HID + j];
    __syncthreads();
    float s = (i == j) ? -1.0f : 0.0f;
    #pragma unroll 4
    for (int k = 0; k < HID; ++k) s += prow[k] * P[k * HID + j];
    Et[(size_t)j * HID + i] = (bf16_t)s;   // Et[col][k] = E[k][col]
}

// ---------- k2: WPt = bf16((W@P)^T), bP = b@P (f32) ----------
__global__ void k_WP(const float* __restrict__ W, const float* __restrict__ b,
                     const float* __restrict__ P,
                     bf16_t* __restrict__ WPt, float* __restrict__ bP) {
    __shared__ float row[HID];
    int i = blockIdx.x, j = threadIdx.x;
    if (i < NF) {
        row[j] = W[i * HID + j];
        __syncthreads();
        float s = 0.f;
        #pragma unroll 4
        for (int k = 0; k < HID; ++k) s += row[k] * P[k * HID + j];
        WPt[(size_t)j * NF + i] = (bf16_t)s;   // WPt[col][k] = (W@P)[k][col]
    } else {
        row[j] = b[j];
        __syncthreads();
        float s = 0.f;
        #pragma unroll 4
        for (int k = 0; k < HID; ++k) s += row[k] * P[k * HID + j];
        bP[j] = s;
    }
}

// ---------- k3: wxp = bf16(LAM * (x@WP + bP)) in scan-ready layout ----------
// scan thread tid of WG g at step t reads bf16x8 pairs at
//   wxp + (t*16+g)*4096 + tid*8         (elems e=0..7  = c{0,1} x r)
//   wxp + (t*16+g)*4096 + 2048 + tid*8  (elems e=8..15 = c{2,3} x r)
__global__ __launch_bounds__(256) void k_wxp(const float* __restrict__ x,
                                             const bf16_t* __restrict__ WPt,
                                             const float* __restrict__ bP,
                                             bf16_t* __restrict__ wxp) {
    int tid = threadIdx.x;
    int lane = tid & 63, w = tid >> 6;
    int quad = lane >> 4, m = lane & 15;
    bf16x8 Bf[4][4];
    float bPv[4];
    #pragma unroll
    for (int c = 0; c < 4; ++c) {
        int col = w * 64 + c * 16 + m;
        bPv[c] = bP[col];
        const bf16_t* wp = WPt + (size_t)col * NF + quad * 8;
        #pragma unroll
        for (int kt = 0; kt < 4; ++kt)
            Bf[c][kt] = *(const bf16x8*)(wp + kt * 32);
    }
    for (int i = 0; i < 8; ++i) {
        int tile = blockIdx.x * 8 + i;          // t*16 + g
        int t = tile >> 4, g = tile & 15;
        const float* xp = x + (((size_t)t * 256 + g * 16 + m) * NF + quad * 8);
        f32x4 acc[4];
        #pragma unroll
        for (int c = 0; c < 4; ++c) acc[c] = (f32x4){bPv[c], bPv[c], bPv[c], bPv[c]};
        #pragma unroll
        for (int kt = 0; kt < 4; ++kt) {
            f32x4 xa = *(const f32x4*)(xp + kt * 32);
            f32x4 xb = *(const f32x4*)(xp + kt * 32 + 4);
            bf16x8 aa;
            #pragma unroll
            for (int j = 0; j < 4; ++j) { aa[j] = (bf16_t)xa[j]; aa[4 + j] = (bf16_t)xb[j]; }
            #pragma unroll
            for (int c = 0; c < 4; ++c)
                acc[c] = __builtin_amdgcn_mfma_f32_16x16x32_bf16(aa, Bf[c][kt], acc[c], 0, 0, 0);
        }
        bf16x8 lo, hi;
        #pragma unroll
        for (int c = 0; c < 2; ++c)
            #pragma unroll
            for (int r = 0; r < 4; ++r) {
                lo[c * 4 + r] = (bf16_t)(LAM * acc[c][r]);
                hi[c * 4 + r] = (bf16_t)(LAM * acc[2 + c][r]);
            }
        size_t tb = (size_t)tile * 4096;
        *(bf16x8*)(wxp + tb + tid * 8)        = lo;
        *(bf16x8*)(wxp + tb + 2048 + tid * 8) = hi;
    }
}

// ---------- k4: scan with precomputed wxp; 16 WGs x 256 threads ----------
__global__ __launch_bounds__(256, 1) void k_scan_pre(const float* __restrict__ h_in,
                                                     const float* __restrict__ alpha,
                                                     const int* __restrict__ Kp,
                                                     const bf16_t* __restrict__ Et,
                                                     const bf16_t* __restrict__ wxp,
                                                     float* __restrict__ out) {
    __shared__ bf16_t S[2][16 * SSTR];
    int g = blockIdx.x;
    int tid = threadIdx.x;
    int lane = tid & 63, w = tid >> 6, quad = lane >> 4, m = lane & 15;
    int colbase = w * 64 + m;

    // B fragments of E for this wave's 64 cols (4 col-tiles x 8 k-tiles), vector loads
    bf16x8 Ef[32];
    #pragma unroll
    for (int c = 0; c < 4; ++c) {
        const bf16_t* ep = Et + (size_t)(colbase + c * 16) * HID + quad * 8;
        #pragma unroll
        for (int kt = 0; kt < 8; ++kt)
            Ef[c * 8 + kt] = *(const bf16x8*)(ep + kt * 32);
    }

    // swizzled LDS offsets (loop-invariant; swizzle bit5 doesn't touch +kt*64 stride)
    const int rd_base = (m * (SSTR * 2) + quad * 16) ^ s_swz(m);
    int woff[16];
    #pragma unroll
    for (int c = 0; c < 4; ++c)
        #pragma unroll
        for (int r = 0; r < 4; ++r) {
            int row = quad * 4 + r, col = colbase + c * 16;
            woff[c * 4 + r] = ((row * SSTR + col) * 2) ^ s_swz(row);
        }

    float a = alpha[0];
    int K = Kp[0];
    if (K < 1 || K > 64) K = 1;

    const bf16_t* wlo = wxp + (size_t)g * 4096 + (size_t)tid * 8;
    const bf16_t* whi = wlo + 2048;
    const long WSTR = 65536;   // elems per timestep (16 tiles * 4096)

    if (K == 1) {
        // K==1: hp==hc -> single scaled state Q = LAM*2*h.
        // pre_l = acc(=LAM*wx + Q@E) + Q;  u = rcp(exp2(pre_l)+1)
        // Q' = fma(-2A, u, fma(B2, Q, A)),  A = 2a*LAM, B2 = 1-2a.  h_out = Q/(2*LAM).
        const float A2 = 2.0f * a * LAM;
        const float B2 = 1.0f - 2.0f * a;
        const f32x2 A2v  = (f32x2){A2, A2};
        const f32x2 NA2v = (f32x2){-2.0f * A2, -2.0f * A2};
        const f32x2 B2v  = (f32x2){B2, B2};
        const f32x2 ONE2 = (f32x2){1.0f, 1.0f};

        // q2[c*2+h] holds rows (2h, 2h+1) of col-tile c, scaled by LAM*2
        f32x2 q2[8];
        #pragma unroll
        for (int c = 0; c < 4; ++c)
            #pragma unroll
            for (int h = 0; h < 2; ++h) {
                f32x2 v;
                #pragma unroll
                for (int rr = 0; rr < 2; ++rr) {
                    int r = 2 * h + rr;
                    int row = quad * 4 + r, col = colbase + c * 16;
                    float hv = h_in[(g * 16 + row) * HID + col];
                    float Q = 2.0f * LAM * hv;
                    v[rr] = Q;
                    *(bf16_t*)((char*)&S[0][0] + woff[c * 4 + r]) = (bf16_t)Q;
                }
                q2[c * 2 + h] = v;
            }
        __syncthreads();

        // 2-deep wx prefetch: loads stay in flight across raw barriers
        bf16x8 wlA = *(const bf16x8*)(wlo);
        bf16x8 whA = *(const bf16x8*)(whi);
        bf16x8 wlB = *(const bf16x8*)(wlo + WSTR);
        bf16x8 whB = *(const bf16x8*)(whi + WSTR);

        auto step = [&](int p, int t) {   // p is a literal at both call sites
            int tpf = (t + 2 < SEQ) ? t + 2 : SEQ - 1;
            bf16x8 wlC = *(const bf16x8*)(wlo + (long)tpf * WSTR);
            bf16x8 whC = *(const bf16x8*)(whi + (long)tpf * WSTR);

            f32x4 acc[4], accb[4];
            #pragma unroll
            for (int r = 0; r < 4; ++r) {
                acc[0][r] = (float)wlA[r];
                acc[1][r] = (float)wlA[4 + r];
                acc[2][r] = (float)whA[r];
                acc[3][r] = (float)whA[4 + r];
            }
            #pragma unroll
            for (int c = 0; c < 4; ++c) accb[c] = (f32x4){0.f, 0.f, 0.f, 0.f};

            const char* sb = (const char*)&S[p][0];
            bf16x8 af[8];
            #pragma unroll
            for (int kt = 0; kt < 8; ++kt)
                af[kt] = *(const bf16x8*)(sb + rd_base + kt * 64);
            // two 4-deep chains per col-tile (8 indep chains total)
            #pragma unroll
            for (int kt = 0; kt < 4; ++kt)
                #pragma unroll
                for (int c = 0; c < 4; ++c)
                    acc[c] = __builtin_amdgcn_mfma_f32_16x16x32_bf16(af[kt], Ef[c * 8 + kt], acc[c], 0, 0, 0);
            #pragma unroll
            for (int kt = 4; kt < 8; ++kt)
                #pragma unroll
                for (int c = 0; c < 4; ++c)
                    accb[c] = __builtin_amdgcn_mfma_f32_16x16x32_bf16(af[kt], Ef[c * 8 + kt], accb[c], 0, 0, 0);

            char* swp = (char*)&S[p ^ 1][0];
            #pragma unroll
            for (int c = 0; c < 4; ++c)
                #pragma unroll
                for (int h = 0; h < 2; ++h) {
                    int pj = c * 2 + h;
                    // packed f32 pairs -> v_pk_add / v_pk_fma
                    f32x2 s1 = (f32x2){acc[c][2 * h]     + accb[c][2 * h],
                                       acc[c][2 * h + 1] + accb[c][2 * h + 1]};
                    f32x2 pre = s1 + q2[pj];
                    float e0 = __builtin_amdgcn_exp2f(pre[0]);
                    float e1 = __builtin_amdgcn_exp2f(pre[1]);
                    f32x2 ep = (f32x2){e0, e1} + ONE2;
                    f32x2 u = (f32x2){__builtin_amdgcn_rcpf(ep[0]),
                                      __builtin_amdgcn_rcpf(ep[1])};
                    f32x2 inner = q2[pj] * B2v + A2v;    // pk_fma (contraction)
                    f32x2 qn = u * NA2v + inner;         // pk_fma
                    q2[pj] = qn;
                    *(bf16_t*)(swp + woff[c * 4 + 2 * h])     = (bf16_t)qn[0];
                    *(bf16_t*)(swp + woff[c * 4 + 2 * h + 1]) = (bf16_t)qn[1];
                }
            // drain LDS only; global prefetches remain in flight
            asm volatile("s_waitcnt lgkmcnt(0)" ::: "memory");
            __builtin_amdgcn_s_barrier();
            __builtin_amdgcn_sched_barrier(0);
            wlA = wlB; whA = whB; wlB = wlC; whB = whC;
        };
        for (int t = 0; t < SEQ; t += 2) { step(0, t); step(1, t + 1); }

        const float OS = 0.5f / LAM;
        #pragma unroll
        for (int c = 0; c < 4; ++c)
            #pragma unroll
            for (int h = 0; h < 2; ++h)
                #pragma unroll
                for (int rr = 0; rr < 2; ++rr) {
                    int r = 2 * h + rr;
                    int row = quad * 4 + r, col = colbase + c * 16;
                    out[(g * 16 + row) * HID + col] = OS * q2[c * 2 + h][rr];
                }
    } else {
        // general K path (not exercised by the bench; kept correct).
        // wxp is LAM-scaled: acc = LAM*wx + LAM*(s@E); sregL = LAM*s; pre_l = LAM*pre.
        float hp[16], hc[16], sregL[16];
        #pragma unroll
        for (int c = 0; c < 4; ++c)
            #pragma unroll
            for (int r = 0; r < 4; ++r) {
                int e = c * 4 + r;
                int row = quad * 4 + r, col = colbase + c * 16;
                float v = h_in[(g * 16 + row) * HID + col];
                hp[e] = v; hc[e] = v; sregL[e] = LAM * 2.0f * v;
                *(bf16_t*)((char*)&S[0][0] + woff[e]) = (bf16_t)(LAM * 2.0f * v);
            }
        float one_ma = 1.0f - a;
        __syncthreads();
        bf16x8 wl = *(const bf16x8*)(wlo);
        bf16x8 wh = *(const bf16x8*)(whi);
        int p = 0;
        for (int t = 0; t < SEQ; ++t) {
            int tn = (t + 1 < SEQ) ? t + 1 : t;
            bf16x8 wln = *(const bf16x8*)(wlo + (long)tn * WSTR);
            bf16x8 whn = *(const bf16x8*)(whi + (long)tn * WSTR);
            for (int k = 0; k < K; ++k) {
                f32x4 acc[4];
                #pragma unroll
                for (int r = 0; r < 4; ++r) {
                    acc[0][r] = (float)wl[r];
                    acc[1][r] = (float)wl[4 + r];
                    acc[2][r] = (float)wh[r];
                    acc[3][r] = (float)wh[4 + r];
                }
                const char* sb = (const char*)&S[p][0];
                #pragma unroll
                for (int kt = 0; kt < 8; ++kt) {
                    bf16x8 af = *(const bf16x8*)(sb + rd_base + kt * 64);
                    #pragma unroll
                    for (int c = 0; c < 4; ++c)
                        acc[c] = __builtin_amdgcn_mfma_f32_16x16x32_bf16(af, Ef[c * 8 + kt], acc[c], 0, 0, 0);
                }
                bool last = (k == K - 1);
                char* swp = (char*)&S[p ^ 1][0];
                #pragma unroll
                for (int c = 0; c < 4; ++c)
                    #pragma unroll
                    for (int r = 0; r < 4; ++r) {
                        int e = c * 4 + r;
                        float pre_l = acc[c][r] + sregL[e];
                        float T = fast_tanh_scaled(pre_l);
                        float hn = a * (T - hp[e]) + one_ma * hc[e];
                        float sn;
                        if (last) { hp[e] = hn; hc[e] = hn; sn = 2.0f * hn; }
                        else      { hc[e] = hn; sn = hn + hp[e]; }
                        sregL[e] = LAM * sn;
                        *(bf16_t*)(swp + woff[e]) = (bf16_t)(LAM * sn);
                    }
                p ^= 1;
                __syncthreads();
            }
            wl = wln; wh = whn;
        }
        #pragma unroll
        for (int c = 0; c < 4; ++c)
            #pragma unroll
            for (int r = 0; r < 4; ++r) {
                int row = quad * 4 + r, col = colbase + c * 16;
                out[(g * 16 + row) * HID + col] = hp[c * 4 + r];
            }
    }
}

// ---------- fallback: fused scan (16 WGs x 256 threads), wxp workspace unavailable ----------
__global__ __launch_bounds__(256, 1) void k_scan_fused(const float* __restrict__ h_in,
                                                 const float* __restrict__ alpha,
                                                 const int* __restrict__ Kp,
                                                 const bf16_t* __restrict__ Et,
                                                 const bf16_t* __restrict__ WPt,
                                                 const float* __restrict__ bP,
                                                 const float* __restrict__ x,
                                                 float* __restrict__ out) {
    __shared__ bf16_t S[2][16 * SSTR];
    int g = blockIdx.x;
    int tid = threadIdx.x;
    int lane = tid & 63, w = tid >> 6, quad = lane >> 4, m = lane & 15;
    int colbase = w * 64 + m;
    bf16x8 Ef[32];
    bf16x8 Wf[16];
    float bPv[4];
    #pragma unroll
    for (int c = 0; c < 4; ++c) {
        int col = colbase + c * 16;
        bPv[c] = bP[col];
        const bf16_t* ep = Et + (size_t)col * HID + quad * 8;
        #pragma unroll
        for (int kt = 0; kt < 8; ++kt)
            Ef[c * 8 + kt] = *(const bf16x8*)(ep + kt * 32);
        const bf16_t* wpp = WPt + (size_t)col * NF + quad * 8;
        #pragma unroll
        for (int kt = 0; kt < 4; ++kt)
            Wf[c * 4 + kt] = *(const bf16x8*)(wpp + kt * 32);
    }
    float hp[16], hc[16], sreg[16];
    int woff[16];
    #pragma unroll
    for (int c = 0; c < 4; ++c)
        #pragma unroll
        for (int r = 0; r < 4; ++r) {
            int e = c * 4 + r;
            int row = quad * 4 + r, col = colbase + c * 16;
            woff[e] = ((row * SSTR + col) * 2) ^ s_swz(row);
            float v = h_in[(g * 16 + row) * HID + col];
            hp[e] = v; hc[e] = v; sreg[e] = 2.0f * v;
            *(bf16_t*)((char*)&S[0][0] + woff[e]) = (bf16_t)(2.0f * v);
        }
    const int rd_base = (m * (SSTR * 2) + quad * 16) ^ s_swz(m);
    float a = alpha[0];
    float one_ma = 1.0f - a;
    int K = Kp[0];
    if (K < 1 || K > 64) K = 1;
    __syncthreads();
    const float* xrow = x + ((g * 16 + m) * NF + quad * 8);
    bf16x8 xf[4];
    #pragma unroll
    for (int kt = 0; kt < 4; ++kt) {
        f32x4 xa = *(const f32x4*)(xrow + kt * 32);
        f32x4 xb = *(const f32x4*)(xrow + kt * 32 + 4);
        bf16x8 f;
        #pragma unroll
        for (int j = 0; j < 4; ++j) { f[j] = (bf16_t)xa[j]; f[4 + j] = (bf16_t)xb[j]; }
        xf[kt] = f;
    }
    int p = 0;
    for (int t = 0; t < SEQ; ++t) {
        int tn = (t + 1 < SEQ) ? t + 1 : t;
        const float* xn = xrow + (size_t)tn * (256 * NF);
        bf16x8 xnf[4];
        #pragma unroll
        for (int kt = 0; kt < 4; ++kt) {
            f32x4 xa = *(const f32x4*)(xn + kt * 32);
            f32x4 xb = *(const f32x4*)(xn + kt * 32 + 4);
            bf16x8 f;
            #pragma unroll
            for (int j = 0; j < 4; ++j) { f[j] = (bf16_t)xa[j]; f[4 + j] = (bf16_t)xb[j]; }
            xnf[kt] = f;
        }
        f32x4 wxacc[4];
        #pragma unroll
        for (int c = 0; c < 4; ++c) wxacc[c] = (f32x4){bPv[c], bPv[c], bPv[c], bPv[c]};
        #pragma unroll
        for (int kt = 0; kt < 4; ++kt)
            #pragma unroll
            for (int c = 0; c < 4; ++c)
                wxacc[c] = __builtin_amdgcn_mfma_f32_16x16x32_bf16(xf[kt], Wf[c * 4 + kt], wxacc[c], 0, 0, 0);
        for (int k = 0; k < K; ++k) {
            f32x4 acc[4];
            #pragma unroll
            for (int c = 0; c < 4; ++c) acc[c] = wxacc[c];
            const char* sb = (const char*)&S[p][0];
            #pragma unroll
            for (int kt = 0; kt < 8; ++kt) {
                bf16x8 af = *(const bf16x8*)(sb + rd_base + kt * 64);
                #pragma unroll
                for (int c = 0; c < 4; ++c)
                    acc[c] = __builtin_amdgcn_mfma_f32_16x16x32_bf16(af, Ef[c * 8 + kt], acc[c], 0, 0, 0);
            }
            bool last = (k == K - 1);
            char* swp = (char*)&S[p ^ 1][0];
            #pragma unroll
            for (int c = 0; c < 4; ++c) {
                #pragma unroll
                for (int r = 0; r < 4; ++r) {
                    int e = c * 4 + r;
                    float pre = acc[c][r] + sreg[e];
                    float T = fast_tanh_scaled(LAM * pre);
                    float hn = a * (T - hp[e]) + one_ma * hc[e];
                    float sn;
                    if (last) { hp[e] = hn; hc[e] = hn; sn = 2.0f * hn; }
                    else      { hc[e] = hn; sn = hn + hp[e]; }
                    sreg[e] = sn;
                    *(bf16_t*)(swp + woff[e]) = (bf16_t)sn;
                }
            }
            p ^= 1;
            __syncthreads();
        }
        #pragma unroll
        for (int kt = 0; kt < 4; ++kt) xf[kt] = xnf[kt];
    }
    #pragma unroll
    for (int c = 0; c < 4; ++c)
        #pragma unroll
        for (int r = 0; r < 4; ++r) {
            int row = quad * 4 + r, col = colbase + c * 16;
            out[(g * 16 + row) * HID + col] = hp[c * 4 + r];
        }
}

extern "C" void kernel_launch(void* const* d_in, const int* in_sizes, int n_in,
                              void* d_out, int out_size, void* d_ws, size_t ws_size,
                              hipStream_t stream) {
    const float* x     = (const float*)d_in[0];
    const float* h     = (const float*)d_in[1];
    const float* W     = (const float*)d_in[2];
    const float* b     = (const float*)d_in[3];
    const float* V     = (const float*)d_in[4];
    const float* V2    = (const float*)d_in[5];
    const float* alpha = (const float*)d_in[6];
    const int*   Kp    = (const int*)d_in[7];

    char* ws = (char*)d_ws;
    float*  P   = (float*)ws;                     // 256 KB
    bf16_t* Et  = (bf16_t*)(ws + (256u << 10));   // 128 KB (E^T)
    bf16_t* WPt = (bf16_t*)(ws + (384u << 10));   // 64 KB ((W@P)^T)
    float*  bP  = (float*)(ws + (448u << 10));    // 1 KB
    bf16_t* wxp = (bf16_t*)(ws + (512u << 10));   // 128 MB (optional)
    size_t need = (512u << 10) + (size_t)SEQ * 16 * 512 * 8 * sizeof(bf16_t);

    hipLaunchKernelGGL(k_P,  dim3(256), dim3(256), 0, stream, V2, V, P);
    hipLaunchKernelGGL(k_E,  dim3(256), dim3(256), 0, stream, P, Et);
    hipLaunchKernelGGL(k_WP, dim3(129), dim3(256), 0, stream, W, b, P, WPt, bP);
    if (ws_size >= need) {
        hipLaunchKernelGGL(k_wxp, dim3(2048), dim3(256), 0, stream, x, WPt, bP, wxp);
        hipLaunchKernelGGL(k_scan_pre, dim3(16), dim3(256), 0, stream, h, alpha, Kp, Et, wxp, (float*)d_out);
    } else {
        hipLaunchKernelGGL(k_scan_fused, dim3(16), dim3(256), 0, stream, h, alpha, Kp, Et, WPt, bP, x, (float*)d_out);
    }
}

// Round 5
// 1093.631 us; speedup vs baseline: 1.7952x; 1.0278x over previous
//
#include <hip/hip_runtime.h>

// ERNN cell on MI355X. Inputs/outputs FLOAT32. Output f32.
// Math: P = V2@V + I;  wxp[t] = x[t]@(W@P) + b@P  (parallel precompute, bf16)
//   per step: s = h_cur + h_prev;  pre = s + s@(P^2 - I) + wxp[t]
//   h_cur = a*(tanh(pre) - h_prev) + (1-a)*h_cur   (K iters, K=1)
// Identity split keeps MFMA operand E = P^2 - I small -> bf16 rounding harmless.
//
// R9 changes (serial-chain theory):
//  - History: R4/R5 (LDS traffic 2x), R8 (VALU -20%) all time-neutral => the step
//    is a fixed latency chain, dominated post-barrier by the 32-ds_read_b128
//    burst (4 waves x full S re-read, ~490cy) + MFMA tail.
//  - Fix: per-wave kt-PERMUTATION [own0, own1, others...]. After the epilogue's
//    lgkmcnt(0) (already required), each wave pre-reads its OWN 2 k-tiles of the
//    new S (it wrote those cols itself -- no barrier needed) so their latency
//    hides under the barrier wait. Post-barrier burst: 32 -> 24 reads, and the
//    8 own-MFMAs issue immediately, covering the remaining read latency.
//  - All register arrays stay compile-time indexed (rule #20); runtime kt only
//    in ds_read addresses (rdoff[i]).
//  - Carried from R8: LAMBDA-prescaled wxp/S/q (exp2 consumes pre directly),
//    2-FMA pk epilogue, S XOR-swizzle, raw s_barrier + lgkmcnt-only drain,
//    2-deep wx prefetch, split acc/accb MFMA chains.

#define HID   256
#define NF    128
#define SEQ   1024
#define SSTR  264    // s LDS row stride in bf16 elems (pad 8; keeps rows 16B-aligned)
#define LAM   2.8853900817779268f   // 2*log2(e)

typedef __bf16 bf16_t;
typedef __bf16 bf16x8 __attribute__((ext_vector_type(8)));
typedef float  f32x4  __attribute__((ext_vector_type(4)));
typedef float  f32x2  __attribute__((ext_vector_type(2)));

__device__ __forceinline__ float fast_tanh_scaled(float pre_l) {
    // pre_l = LAM * pre;  tanh(pre) = 1 - 2/(exp2(pre_l)+1)
    float e = __builtin_amdgcn_exp2f(pre_l);
    return 1.0f - 2.0f * __builtin_amdgcn_rcpf(e + 1.0f);
}

// physical byte offset of S element (row,col) = ((row*SSTR+col)*2) ^ (parity(row>>2)<<5)
__device__ __forceinline__ int s_swz(int row) {
    return (((row >> 2) ^ (row >> 3)) & 1) << 5;
}

// ---------- k0: P = V2@V + I (f32) ----------
__global__ void k_P(const float* __restrict__ V2, const float* __restrict__ V,
                    float* __restrict__ P) {
    __shared__ float v2row[64];
    int i = blockIdx.x, j = threadIdx.x;
    if (j < 64) v2row[j] = V2[i * 64 + j];
    __syncthreads();
    float s = (i == j) ? 1.0f : 0.0f;
    #pragma unroll 4
    for (int v = 0; v < 64; ++v) s += v2row[v] * V[v * HID + j];
    P[i * HID + j] = s;
}

// ---------- k1: Et = bf16((P@P - I)^T)  (transposed -> vector B-frag loads) ----------
__global__ void k_E(const float* __restrict__ P, bf16_t* __restrict__ Et) {
    __shared__ float prow[HID];
    int i = blockIdx.x, j = threadIdx.x;
    prow[j] = P[i * HID + j];
    __syncthreads();
    float s = (i == j) ? -1.0f : 0.0f;
    #pragma unroll 4
    for (int k = 0; k < HID; ++k) s += prow[k] * P[k * HID + j];
    Et[(size_t)j * HID + i] = (bf16_t)s;   // Et[col][k] = E[k][col]
}

// ---------- k2: WPt = bf16((W@P)^T), bP = b@P (f32) ----------
__global__ void k_WP(const float* __restrict__ W, const float* __restrict__ b,
                     const float* __restrict__ P,
                     bf16_t* __restrict__ WPt, float* __restrict__ bP) {
    __shared__ float row[HID];
    int i = blockIdx.x, j = threadIdx.x;
    if (i < NF) {
        row[j] = W[i * HID + j];
        __syncthreads();
        float s = 0.f;
        #pragma unroll 4
        for (int k = 0; k < HID; ++k) s += row[k] * P[k * HID + j];
        WPt[(size_t)j * NF + i] = (bf16_t)s;   // WPt[col][k] = (W@P)[k][col]
    } else {
        row[j] = b[j];
        __syncthreads();
        float s = 0.f;
        #pragma unroll 4
        for (int k = 0; k < HID; ++k) s += row[k] * P[k * HID + j];
        bP[j] = s;
    }
}

// ---------- k3: wxp = bf16(LAM * (x@WP + bP)) in scan-ready layout ----------
// scan thread tid of WG g at step t reads bf16x8 pairs at
//   wxp + (t*16+g)*4096 + tid*8         (elems e=0..7  = c{0,1} x r)
//   wxp + (t*16+g)*4096 + 2048 + tid*8  (elems e=8..15 = c{2,3} x r)
__global__ __launch_bounds__(256) void k_wxp(const float* __restrict__ x,
                                             const bf16_t* __restrict__ WPt,
                                             const float* __restrict__ bP,
                                             bf16_t* __restrict__ wxp) {
    int tid = threadIdx.x;
    int lane = tid & 63, w = tid >> 6;
    int quad = lane >> 4, m = lane & 15;
    bf16x8 Bf[4][4];
    float bPv[4];
    #pragma unroll
    for (int c = 0; c < 4; ++c) {
        int col = w * 64 + c * 16 + m;
        bPv[c] = bP[col];
        const bf16_t* wp = WPt + (size_t)col * NF + quad * 8;
        #pragma unroll
        for (int kt = 0; kt < 4; ++kt)
            Bf[c][kt] = *(const bf16x8*)(wp + kt * 32);
    }
    for (int i = 0; i < 8; ++i) {
        int tile = blockIdx.x * 8 + i;          // t*16 + g
        int t = tile >> 4, g = tile & 15;
        const float* xp = x + (((size_t)t * 256 + g * 16 + m) * NF + quad * 8);
        f32x4 acc[4];
        #pragma unroll
        for (int c = 0; c < 4; ++c) acc[c] = (f32x4){bPv[c], bPv[c], bPv[c], bPv[c]};
        #pragma unroll
        for (int kt = 0; kt < 4; ++kt) {
            f32x4 xa = *(const f32x4*)(xp + kt * 32);
            f32x4 xb = *(const f32x4*)(xp + kt * 32 + 4);
            bf16x8 aa;
            #pragma unroll
            for (int j = 0; j < 4; ++j) { aa[j] = (bf16_t)xa[j]; aa[4 + j] = (bf16_t)xb[j]; }
            #pragma unroll
            for (int c = 0; c < 4; ++c)
                acc[c] = __builtin_amdgcn_mfma_f32_16x16x32_bf16(aa, Bf[c][kt], acc[c], 0, 0, 0);
        }
        bf16x8 lo, hi;
        #pragma unroll
        for (int c = 0; c < 2; ++c)
            #pragma unroll
            for (int r = 0; r < 4; ++r) {
                lo[c * 4 + r] = (bf16_t)(LAM * acc[c][r]);
                hi[c * 4 + r] = (bf16_t)(LAM * acc[2 + c][r]);
            }
        size_t tb = (size_t)tile * 4096;
        *(bf16x8*)(wxp + tb + tid * 8)        = lo;
        *(bf16x8*)(wxp + tb + 2048 + tid * 8) = hi;
    }
}

// ---------- k4: scan with precomputed wxp; 16 WGs x 256 threads ----------
__global__ __launch_bounds__(256, 1) void k_scan_pre(const float* __restrict__ h_in,
                                                     const float* __restrict__ alpha,
                                                     const int* __restrict__ Kp,
                                                     const bf16_t* __restrict__ Et,
                                                     const bf16_t* __restrict__ wxp,
                                                     float* __restrict__ out) {
    __shared__ bf16_t S[2][16 * SSTR];
    int g = blockIdx.x;
    int tid = threadIdx.x;
    int lane = tid & 63, w = tid >> 6, quad = lane >> 4, m = lane & 15;
    int colbase = w * 64 + m;

    const int rd_base = (m * (SSTR * 2) + quad * 16) ^ s_swz(m);

    // Per-wave kt-PERMUTATION: slot i -> ktp(i); slots 0,1 = this wave's OWN
    // k-tiles (2w, 2w+1), slots 2..7 = the other 6 in ascending order.
    // Ef/rdoff are indexed by the compile-time slot i everywhere in the loop;
    // the runtime kt lives only in addresses.
    int rdoff[8];
    bf16x8 Ef[32];
    #pragma unroll
    for (int i = 0; i < 8; ++i) {
        int j = i - 2;
        int kt = (i < 2) ? (2 * w + i) : (j + ((j >= 2 * w) ? 2 : 0));
        rdoff[i] = rd_base + kt * 64;
        #pragma unroll
        for (int c = 0; c < 4; ++c)
            Ef[c * 8 + i] = *(const bf16x8*)(Et + (size_t)(colbase + c * 16) * HID
                                             + quad * 8 + kt * 32);
    }

    int woff[16];
    #pragma unroll
    for (int c = 0; c < 4; ++c)
        #pragma unroll
        for (int r = 0; r < 4; ++r) {
            int row = quad * 4 + r, col = colbase + c * 16;
            woff[c * 4 + r] = ((row * SSTR + col) * 2) ^ s_swz(row);
        }

    float a = alpha[0];
    int K = Kp[0];
    if (K < 1 || K > 64) K = 1;

    const bf16_t* wlo = wxp + (size_t)g * 4096 + (size_t)tid * 8;
    const bf16_t* whi = wlo + 2048;
    const long WSTR = 65536;   // elems per timestep (16 tiles * 4096)

    if (K == 1) {
        // K==1: hp==hc -> single scaled state Q = LAM*2*h.
        // pre_l = acc(=LAM*wx + Q@E) + Q;  u = rcp(exp2(pre_l)+1)
        // Q' = fma(-2A, u, fma(B2, Q, A)),  A = 2a*LAM, B2 = 1-2a.  h_out = Q/(2*LAM).
        const float A2 = 2.0f * a * LAM;
        const float B2 = 1.0f - 2.0f * a;
        const f32x2 A2v  = (f32x2){A2, A2};
        const f32x2 NA2v = (f32x2){-2.0f * A2, -2.0f * A2};
        const f32x2 B2v  = (f32x2){B2, B2};
        const f32x2 ONE2 = (f32x2){1.0f, 1.0f};

        // q2[c*2+h] holds rows (2h, 2h+1) of col-tile c, scaled by LAM*2
        f32x2 q2[8];
        #pragma unroll
        for (int c = 0; c < 4; ++c)
            #pragma unroll
            for (int h = 0; h < 2; ++h) {
                f32x2 v;
                #pragma unroll
                for (int rr = 0; rr < 2; ++rr) {
                    int r = 2 * h + rr;
                    int row = quad * 4 + r, col = colbase + c * 16;
                    float hv = h_in[(g * 16 + row) * HID + col];
                    float Q = 2.0f * LAM * hv;
                    v[rr] = Q;
                    *(bf16_t*)((char*)&S[0][0] + woff[c * 4 + r]) = (bf16_t)Q;
                }
                q2[c * 2 + h] = v;
            }
        __syncthreads();

        // own k-tiles of the initial S (this wave's cols) -> registers
        bf16x8 af_own0 = *(const bf16x8*)((const char*)&S[0][0] + rdoff[0]);
        bf16x8 af_own1 = *(const bf16x8*)((const char*)&S[0][0] + rdoff[1]);

        // 2-deep wx prefetch: loads stay in flight across raw barriers
        bf16x8 wlA = *(const bf16x8*)(wlo);
        bf16x8 whA = *(const bf16x8*)(whi);
        bf16x8 wlB = *(const bf16x8*)(wlo + WSTR);
        bf16x8 whB = *(const bf16x8*)(whi + WSTR);

        auto step = [&](int p, int t) {   // p is a literal at both call sites
            int tpf = (t + 2 < SEQ) ? t + 2 : SEQ - 1;
            bf16x8 wlC = *(const bf16x8*)(wlo + (long)tpf * WSTR);
            bf16x8 whC = *(const bf16x8*)(whi + (long)tpf * WSTR);

            // issue the 6 OTHER-wave k-tile reads (post-barrier burst: 24/CU)
            const char* sb = (const char*)&S[p][0];
            bf16x8 af2 = *(const bf16x8*)(sb + rdoff[2]);
            bf16x8 af3 = *(const bf16x8*)(sb + rdoff[3]);
            bf16x8 af4 = *(const bf16x8*)(sb + rdoff[4]);
            bf16x8 af5 = *(const bf16x8*)(sb + rdoff[5]);
            bf16x8 af6 = *(const bf16x8*)(sb + rdoff[6]);
            bf16x8 af7 = *(const bf16x8*)(sb + rdoff[7]);

            f32x4 acc[4], accb[4];
            #pragma unroll
            for (int r = 0; r < 4; ++r) {
                acc[0][r] = (float)wlA[r];
                acc[1][r] = (float)wlA[4 + r];
                acc[2][r] = (float)whA[r];
                acc[3][r] = (float)whA[4 + r];
            }
            #pragma unroll
            for (int c = 0; c < 4; ++c) accb[c] = (f32x4){0.f, 0.f, 0.f, 0.f};

            // own MFMAs first (fragments pre-read before the barrier -> ready now,
            // they cover the other-fragment read latency)
            #pragma unroll
            for (int c = 0; c < 4; ++c)
                acc[c] = __builtin_amdgcn_mfma_f32_16x16x32_bf16(af_own0, Ef[c * 8 + 0], acc[c], 0, 0, 0);
            #pragma unroll
            for (int c = 0; c < 4; ++c)
                acc[c] = __builtin_amdgcn_mfma_f32_16x16x32_bf16(af_own1, Ef[c * 8 + 1], acc[c], 0, 0, 0);
            #pragma unroll
            for (int c = 0; c < 4; ++c)
                acc[c] = __builtin_amdgcn_mfma_f32_16x16x32_bf16(af2, Ef[c * 8 + 2], acc[c], 0, 0, 0);
            #pragma unroll
            for (int c = 0; c < 4; ++c)
                acc[c] = __builtin_amdgcn_mfma_f32_16x16x32_bf16(af3, Ef[c * 8 + 3], acc[c], 0, 0, 0);
            #pragma unroll
            for (int c = 0; c < 4; ++c)
                accb[c] = __builtin_amdgcn_mfma_f32_16x16x32_bf16(af4, Ef[c * 8 + 4], accb[c], 0, 0, 0);
            #pragma unroll
            for (int c = 0; c < 4; ++c)
                accb[c] = __builtin_amdgcn_mfma_f32_16x16x32_bf16(af5, Ef[c * 8 + 5], accb[c], 0, 0, 0);
            #pragma unroll
            for (int c = 0; c < 4; ++c)
                accb[c] = __builtin_amdgcn_mfma_f32_16x16x32_bf16(af6, Ef[c * 8 + 6], accb[c], 0, 0, 0);
            #pragma unroll
            for (int c = 0; c < 4; ++c)
                accb[c] = __builtin_amdgcn_mfma_f32_16x16x32_bf16(af7, Ef[c * 8 + 7], accb[c], 0, 0, 0);

            char* swp = (char*)&S[p ^ 1][0];
            #pragma unroll
            for (int c = 0; c < 4; ++c)
                #pragma unroll
                for (int h = 0; h < 2; ++h) {
                    int pj = c * 2 + h;
                    f32x2 s1 = (f32x2){acc[c][2 * h]     + accb[c][2 * h],
                                       acc[c][2 * h + 1] + accb[c][2 * h + 1]};
                    f32x2 pre = s1 + q2[pj];
                    float e0 = __builtin_amdgcn_exp2f(pre[0]);
                    float e1 = __builtin_amdgcn_exp2f(pre[1]);
                    f32x2 ep = (f32x2){e0, e1} + ONE2;
                    f32x2 u = (f32x2){__builtin_amdgcn_rcpf(ep[0]),
                                      __builtin_amdgcn_rcpf(ep[1])};
                    f32x2 inner = q2[pj] * B2v + A2v;    // pk_fma (contraction)
                    f32x2 qn = u * NA2v + inner;         // pk_fma
                    q2[pj] = qn;
                    *(bf16_t*)(swp + woff[c * 4 + 2 * h])     = (bf16_t)qn[0];
                    *(bf16_t*)(swp + woff[c * 4 + 2 * h + 1]) = (bf16_t)qn[1];
                }
            // drain LDS writes (needed before barrier anyway), then pre-read
            // OUR OWN k-tiles of the new S -- no barrier needed for own cols;
            // their latency hides under the barrier wait.
            asm volatile("s_waitcnt lgkmcnt(0)" ::: "memory");
            af_own0 = *(const bf16x8*)(swp + rdoff[0]);
            af_own1 = *(const bf16x8*)(swp + rdoff[1]);
            __builtin_amdgcn_s_barrier();
            __builtin_amdgcn_sched_barrier(0);
            wlA = wlB; whA = whB; wlB = wlC; whB = whC;
        };
        for (int t = 0; t < SEQ; t += 2) { step(0, t); step(1, t + 1); }

        const float OS = 0.5f / LAM;
        #pragma unroll
        for (int c = 0; c < 4; ++c)
            #pragma unroll
            for (int h = 0; h < 2; ++h)
                #pragma unroll
                for (int rr = 0; rr < 2; ++rr) {
                    int r = 2 * h + rr;
                    int row = quad * 4 + r, col = colbase + c * 16;
                    out[(g * 16 + row) * HID + col] = OS * q2[c * 2 + h][rr];
                }
    } else {
        // general K path (not exercised by the bench; kept correct).
        // wxp is LAM-scaled: acc = LAM*wx + LAM*(s@E); sregL = LAM*s; pre_l = LAM*pre.
        float hp[16], hc[16], sregL[16];
        #pragma unroll
        for (int c = 0; c < 4; ++c)
            #pragma unroll
            for (int r = 0; r < 4; ++r) {
                int e = c * 4 + r;
                int row = quad * 4 + r, col = colbase + c * 16;
                float v = h_in[(g * 16 + row) * HID + col];
                hp[e] = v; hc[e] = v; sregL[e] = LAM * 2.0f * v;
                *(bf16_t*)((char*)&S[0][0] + woff[e]) = (bf16_t)(LAM * 2.0f * v);
            }
        float one_ma = 1.0f - a;
        __syncthreads();
        bf16x8 wl = *(const bf16x8*)(wlo);
        bf16x8 wh = *(const bf16x8*)(whi);
        int p = 0;
        for (int t = 0; t < SEQ; ++t) {
            int tn = (t + 1 < SEQ) ? t + 1 : t;
            bf16x8 wln = *(const bf16x8*)(wlo + (long)tn * WSTR);
            bf16x8 whn = *(const bf16x8*)(whi + (long)tn * WSTR);
            for (int k = 0; k < K; ++k) {
                f32x4 acc[4];
                #pragma unroll
                for (int r = 0; r < 4; ++r) {
                    acc[0][r] = (float)wl[r];
                    acc[1][r] = (float)wl[4 + r];
                    acc[2][r] = (float)wh[r];
                    acc[3][r] = (float)wh[4 + r];
                }
                const char* sb = (const char*)&S[p][0];
                #pragma unroll
                for (int i = 0; i < 8; ++i) {
                    bf16x8 af = *(const bf16x8*)(sb + rdoff[i]);
                    #pragma unroll
                    for (int c = 0; c < 4; ++c)
                        acc[c] = __builtin_amdgcn_mfma_f32_16x16x32_bf16(af, Ef[c * 8 + i], acc[c], 0, 0, 0);
                }
                bool last = (k == K - 1);
                char* swp = (char*)&S[p ^ 1][0];
                #pragma unroll
                for (int c = 0; c < 4; ++c)
                    #pragma unroll
                    for (int r = 0; r < 4; ++r) {
                        int e = c * 4 + r;
                        float pre_l = acc[c][r] + sregL[e];
                        float T = fast_tanh_scaled(pre_l);
                        float hn = a * (T - hp[e]) + one_ma * hc[e];
                        float sn;
                        if (last) { hp[e] = hn; hc[e] = hn; sn = 2.0f * hn; }
                        else      { hc[e] = hn; sn = hn + hp[e]; }
                        sregL[e] = LAM * sn;
                        *(bf16_t*)(swp + woff[e]) = (bf16_t)(LAM * sn);
                    }
                p ^= 1;
                __syncthreads();
            }
            wl = wln; wh = whn;
        }
        #pragma unroll
        for (int c = 0; c < 4; ++c)
            #pragma unroll
            for (int r = 0; r < 4; ++r) {
                int row = quad * 4 + r, col = colbase + c * 16;
                out[(g * 16 + row) * HID + col] = hp[c * 4 + r];
            }
    }
}

// ---------- fallback: fused scan (16 WGs x 256 threads), wxp workspace unavailable ----------
__global__ __launch_bounds__(256, 1) void k_scan_fused(const float* __restrict__ h_in,
                                                 const float* __restrict__ alpha,
                                                 const int* __restrict__ Kp,
                                                 const bf16_t* __restrict__ Et,
                                                 const bf16_t* __restrict__ WPt,
                                                 const float* __restrict__ bP,
                                                 const float* __restrict__ x,
                                                 float* __restrict__ out) {
    __shared__ bf16_t S[2][16 * SSTR];
    int g = blockIdx.x;
    int tid = threadIdx.x;
    int lane = tid & 63, w = tid >> 6, quad = lane >> 4, m = lane & 15;
    int colbase = w * 64 + m;
    bf16x8 Ef[32];
    bf16x8 Wf[16];
    float bPv[4];
    #pragma unroll
    for (int c = 0; c < 4; ++c) {
        int col = colbase + c * 16;
        bPv[c] = bP[col];
        const bf16_t* ep = Et + (size_t)col * HID + quad * 8;
        #pragma unroll
        for (int kt = 0; kt < 8; ++kt)
            Ef[c * 8 + kt] = *(const bf16x8*)(ep + kt * 32);
        const bf16_t* wpp = WPt + (size_t)col * NF + quad * 8;
        #pragma unroll
        for (int kt = 0; kt < 4; ++kt)
            Wf[c * 4 + kt] = *(const bf16x8*)(wpp + kt * 32);
    }
    float hp[16], hc[16], sreg[16];
    int woff[16];
    #pragma unroll
    for (int c = 0; c < 4; ++c)
        #pragma unroll
        for (int r = 0; r < 4; ++r) {
            int e = c * 4 + r;
            int row = quad * 4 + r, col = colbase + c * 16;
            woff[e] = ((row * SSTR + col) * 2) ^ s_swz(row);
            float v = h_in[(g * 16 + row) * HID + col];
            hp[e] = v; hc[e] = v; sreg[e] = 2.0f * v;
            *(bf16_t*)((char*)&S[0][0] + woff[e]) = (bf16_t)(2.0f * v);
        }
    const int rd_base = (m * (SSTR * 2) + quad * 16) ^ s_swz(m);
    float a = alpha[0];
    float one_ma = 1.0f - a;
    int K = Kp[0];
    if (K < 1 || K > 64) K = 1;
    __syncthreads();
    const float* xrow = x + ((g * 16 + m) * NF + quad * 8);
    bf16x8 xf[4];
    #pragma unroll
    for (int kt = 0; kt < 4; ++kt) {
        f32x4 xa = *(const f32x4*)(xrow + kt * 32);
        f32x4 xb = *(const f32x4*)(xrow + kt * 32 + 4);
        bf16x8 f;
        #pragma unroll
        for (int j = 0; j < 4; ++j) { f[j] = (bf16_t)xa[j]; f[4 + j] = (bf16_t)xb[j]; }
        xf[kt] = f;
    }
    int p = 0;
    for (int t = 0; t < SEQ; ++t) {
        int tn = (t + 1 < SEQ) ? t + 1 : t;
        const float* xn = xrow + (size_t)tn * (256 * NF);
        bf16x8 xnf[4];
        #pragma unroll
        for (int kt = 0; kt < 4; ++kt) {
            f32x4 xa = *(const f32x4*)(xn + kt * 32);
            f32x4 xb = *(const f32x4*)(xn + kt * 32 + 4);
            bf16x8 f;
            #pragma unroll
            for (int j = 0; j < 4; ++j) { f[j] = (bf16_t)xa[j]; f[4 + j] = (bf16_t)xb[j]; }
            xnf[kt] = f;
        }
        f32x4 wxacc[4];
        #pragma unroll
        for (int c = 0; c < 4; ++c) wxacc[c] = (f32x4){bPv[c], bPv[c], bPv[c], bPv[c]};
        #pragma unroll
        for (int kt = 0; kt < 4; ++kt)
            #pragma unroll
            for (int c = 0; c < 4; ++c)
                wxacc[c] = __builtin_amdgcn_mfma_f32_16x16x32_bf16(xf[kt], Wf[c * 4 + kt], wxacc[c], 0, 0, 0);
        for (int k = 0; k < K; ++k) {
            f32x4 acc[4];
            #pragma unroll
            for (int c = 0; c < 4; ++c) acc[c] = wxacc[c];
            const char* sb = (const char*)&S[p][0];
            #pragma unroll
            for (int kt = 0; kt < 8; ++kt) {
                bf16x8 af = *(const bf16x8*)(sb + rd_base + kt * 64);
                #pragma unroll
                for (int c = 0; c < 4; ++c)
                    acc[c] = __builtin_amdgcn_mfma_f32_16x16x32_bf16(af, Ef[c * 8 + kt], acc[c], 0, 0, 0);
            }
            bool last = (k == K - 1);
            char* swp = (char*)&S[p ^ 1][0];
            #pragma unroll
            for (int c = 0; c < 4; ++c) {
                #pragma unroll
                for (int r = 0; r < 4; ++r) {
                    int e = c * 4 + r;
                    float pre = acc[c][r] + sreg[e];
                    float T = fast_tanh_scaled(LAM * pre);
                    float hn = a * (T - hp[e]) + one_ma * hc[e];
                    float sn;
                    if (last) { hp[e] = hn; hc[e] = hn; sn = 2.0f * hn; }
                    else      { hc[e] = hn; sn = hn + hp[e]; }
                    sreg[e] = sn;
                    *(bf16_t*)(swp + woff[e]) = (bf16_t)sn;
                }
            }
            p ^= 1;
            __syncthreads();
        }
        #pragma unroll
        for (int kt = 0; kt < 4; ++kt) xf[kt] = xnf[kt];
    }
    #pragma unroll
    for (int c = 0; c < 4; ++c)
        #pragma unroll
        for (int r = 0; r < 4; ++r) {
            int row = quad * 4 + r, col = colbase + c * 16;
            out[(g * 16 + row) * HID + col] = hp[c * 4 + r];
        }
}

extern "C" void kernel_launch(void* const* d_in, const int* in_sizes, int n_in,
                              void* d_out, int out_size, void* d_ws, size_t ws_size,
                              hipStream_t stream) {
    const float* x     = (const float*)d_in[0];
    const float* h     = (const float*)d_in[1];
    const float* W     = (const float*)d_in[2];
    const float* b     = (const float*)d_in[3];
    const float* V     = (const float*)d_in[4];
    const float* V2    = (const float*)d_in[5];
    const float* alpha = (const float*)d_in[6];
    const int*   Kp    = (const int*)d_in[7];

    char* ws = (char*)d_ws;
    float*  P   = (float*)ws;                     // 256 KB
    bf16_t* Et  = (bf16_t*)(ws + (256u << 10));   // 128 KB (E^T)
    bf16_t* WPt = (bf16_t*)(ws + (384u << 10));   // 64 KB ((W@P)^T)
    float*  bP  = (float*)(ws + (448u << 10));    // 1 KB
    bf16_t* wxp = (bf16_t*)(ws + (512u << 10));   // 128 MB (optional)
    size_t need = (512u << 10) + (size_t)SEQ * 16 * 512 * 8 * sizeof(bf16_t);

    hipLaunchKernelGGL(k_P,  dim3(256), dim3(256), 0, stream, V2, V, P);
    hipLaunchKernelGGL(k_E,  dim3(256), dim3(256), 0, stream, P, Et);
    hipLaunchKernelGGL(k_WP, dim3(129), dim3(256), 0, stream, W, b, P, WPt, bP);
    if (ws_size >= need) {
        hipLaunchKernelGGL(k_wxp, dim3(2048), dim3(256), 0, stream, x, WPt, bP, wxp);
        hipLaunchKernelGGL(k_scan_pre, dim3(16), dim3(256), 0, stream, h, alpha, Kp, Et, wxp, (float*)d_out);
    } else {
        hipLaunchKernelGGL(k_scan_fused, dim3(16), dim3(256), 0, stream, h, alpha, Kp, Et, WPt, bP, x, (float*)d_out);
    }
}

// Round 6
// 972.978 us; speedup vs baseline: 2.0178x; 1.1240x over previous
//
#include <hip/hip_runtime.h>

// ERNN cell on MI355X. Inputs/outputs FLOAT32. Output f32.
// Math: P = V2@V + I;  wxp[t] = x[t]@(W@P) + b@P  (parallel precompute, bf16)
//   per step: s = h_cur + h_prev;  pre = s + s@(P^2 - I) + wxp[t]
//   h_cur = a*(tanh(pre) - h_prev) + (1-a)*h_cur   (K iters, K=1)
// Identity split keeps MFMA operand E = P^2 - I small -> bf16 rounding harmless.
//
// R10 changes (transposed-product epilogue):
//  - Compute preT = E^T @ sT instead of s @ E. MFMA A/B fragments are layout-
//    mirror-symmetric, so ALL existing loads keep their addresses (Ef becomes the
//    A-operand, the S-row read becomes the B-operand); only mfma arg order swaps.
//    C-layout now gives each lane 4 runs of 4 CONSECUTIVE hidden cols at a fixed
//    batch row m=lane&15:
//      * 16 ds_write_b16 -> 4 ds_write_b64 (packed bf16x4, cvt_pk)
//      * q-state = 4x f32x4, fully packed (pk_add/pk_fma) epilogue
//      * h_in/out become f32x4 loads/stores
//      * read AND write LDS row = m per lane -> one swizzle term s_swz(m)
//  - k_wxp transposed identically (operand swap + f32x4 bP init); per-thread
//    wxp layout contract unchanged.
//  - Carried from R9: own-k-tile pre-barrier reads, kt-permutation, LAM-prescale,
//    raw s_barrier + lgkmcnt-only drain, 2-deep wx prefetch, split acc/accb.

#define HID   256
#define NF    128
#define SEQ   1024
#define SSTR  264    // s LDS row stride in bf16 elems (pad 8; rows 16B-aligned)
#define LAM   2.8853900817779268f   // 2*log2(e)

typedef __bf16 bf16_t;
typedef __bf16 bf16x4 __attribute__((ext_vector_type(4)));
typedef __bf16 bf16x8 __attribute__((ext_vector_type(8)));
typedef float  f32x4  __attribute__((ext_vector_type(4)));

__device__ __forceinline__ float fast_tanh_scaled(float pre_l) {
    // pre_l = LAM * pre;  tanh(pre) = 1 - 2/(exp2(pre_l)+1)
    float e = __builtin_amdgcn_exp2f(pre_l);
    return 1.0f - 2.0f * __builtin_amdgcn_rcpf(e + 1.0f);
}

// swizzle: phys = logical ^ (parity((row>>2)^(row>>3)) << 5); mask changes only
// at 4-row (2112B = 33*64) boundaries -> 64B-block-safe, bijective.
__device__ __forceinline__ int s_swz(int row) {
    return (((row >> 2) ^ (row >> 3)) & 1) << 5;
}

// ---------- k0: P = V2@V + I (f32) ----------
__global__ void k_P(const float* __restrict__ V2, const float* __restrict__ V,
                    float* __restrict__ P) {
    __shared__ float v2row[64];
    int i = blockIdx.x, j = threadIdx.x;
    if (j < 64) v2row[j] = V2[i * 64 + j];
    __syncthreads();
    float s = (i == j) ? 1.0f : 0.0f;
    #pragma unroll 4
    for (int v = 0; v < 64; ++v) s += v2row[v] * V[v * HID + j];
    P[i * HID + j] = s;
}

// ---------- k1: Et = bf16((P@P - I)^T) ----------
__global__ void k_E(const float* __restrict__ P, bf16_t* __restrict__ Et) {
    __shared__ float prow[HID];
    int i = blockIdx.x, j = threadIdx.x;
    prow[j] = P[i * HID + j];
    __syncthreads();
    float s = (i == j) ? -1.0f : 0.0f;
    #pragma unroll 4
    for (int k = 0; k < HID; ++k) s += prow[k] * P[k * HID + j];
    Et[(size_t)j * HID + i] = (bf16_t)s;   // Et[col][k] = E[k][col]
}

// ---------- k2: WPt = bf16((W@P)^T), bP = b@P (f32) ----------
__global__ void k_WP(const float* __restrict__ W, const float* __restrict__ b,
                     const float* __restrict__ P,
                     bf16_t* __restrict__ WPt, float* __restrict__ bP) {
    __shared__ float row[HID];
    int i = blockIdx.x, j = threadIdx.x;
    if (i < NF) {
        row[j] = W[i * HID + j];
        __syncthreads();
        float s = 0.f;
        #pragma unroll 4
        for (int k = 0; k < HID; ++k) s += row[k] * P[k * HID + j];
        WPt[(size_t)j * NF + i] = (bf16_t)s;   // WPt[col][k] = (W@P)[k][col]
    } else {
        row[j] = b[j];
        __syncthreads();
        float s = 0.f;
        #pragma unroll 4
        for (int k = 0; k < HID; ++k) s += row[k] * P[k * HID + j];
        bP[j] = s;
    }
}

// ---------- k3: wxp = bf16(LAM * (x@WP + bP)^T-layout) ----------
// Transposed product: C = (WP)^T-tiles @ x^T. Per thread: acc[c][r] =
// wx[batch m][hidden w*64+c*16+quad*4+r]. Stored per thread as 2 bf16x8 at
//   tile*4096 + tid*8  (c=0,1)  and  tile*4096 + 2048 + tid*8  (c=2,3).
__global__ __launch_bounds__(256) void k_wxp(const float* __restrict__ x,
                                             const bf16_t* __restrict__ WPt,
                                             const float* __restrict__ bP,
                                             bf16_t* __restrict__ wxp) {
    int tid = threadIdx.x;
    int lane = tid & 63, w = tid >> 6;
    int quad = lane >> 4, m = lane & 15;
    bf16x8 Af[4][4];           // (W@P)^T fragments, A-operand
    f32x4 bPv4[4];
    #pragma unroll
    for (int c = 0; c < 4; ++c) {
        bPv4[c] = *(const f32x4*)(bP + w * 64 + c * 16 + quad * 4);
        const bf16_t* wp = WPt + (size_t)(w * 64 + c * 16 + m) * NF + quad * 8;
        #pragma unroll
        for (int kt = 0; kt < 4; ++kt)
            Af[c][kt] = *(const bf16x8*)(wp + kt * 32);
    }
    for (int i = 0; i < 8; ++i) {
        int tile = blockIdx.x * 8 + i;          // t*16 + g
        int t = tile >> 4, g = tile & 15;
        const float* xp = x + (((size_t)t * 256 + g * 16 + m) * NF + quad * 8);
        f32x4 acc[4];
        #pragma unroll
        for (int c = 0; c < 4; ++c) acc[c] = bPv4[c];
        #pragma unroll
        for (int kt = 0; kt < 4; ++kt) {
            f32x4 xa = *(const f32x4*)(xp + kt * 32);
            f32x4 xb = *(const f32x4*)(xp + kt * 32 + 4);
            bf16x8 bb;                           // x^T fragment, B-operand
            #pragma unroll
            for (int j = 0; j < 4; ++j) { bb[j] = (bf16_t)xa[j]; bb[4 + j] = (bf16_t)xb[j]; }
            #pragma unroll
            for (int c = 0; c < 4; ++c)
                acc[c] = __builtin_amdgcn_mfma_f32_16x16x32_bf16(Af[c][kt], bb, acc[c], 0, 0, 0);
        }
        bf16x8 lo, hi;
        #pragma unroll
        for (int c = 0; c < 2; ++c)
            #pragma unroll
            for (int r = 0; r < 4; ++r) {
                lo[c * 4 + r] = (bf16_t)(LAM * acc[c][r]);
                hi[c * 4 + r] = (bf16_t)(LAM * acc[2 + c][r]);
            }
        size_t tb = (size_t)tile * 4096;
        *(bf16x8*)(wxp + tb + tid * 8)        = lo;
        *(bf16x8*)(wxp + tb + 2048 + tid * 8) = hi;
    }
}

// ---------- k4: scan with precomputed wxp; 16 WGs x 256 threads ----------
__global__ __launch_bounds__(256, 1) void k_scan_pre(const float* __restrict__ h_in,
                                                     const float* __restrict__ alpha,
                                                     const int* __restrict__ Kp,
                                                     const bf16_t* __restrict__ Et,
                                                     const bf16_t* __restrict__ wxp,
                                                     float* __restrict__ out) {
    __shared__ bf16_t S[2][16 * SSTR];
    int g = blockIdx.x;
    int tid = threadIdx.x;
    int lane = tid & 63, w = tid >> 6, quad = lane >> 4, m = lane & 15;

    const int rd_base = (m * (SSTR * 2) + quad * 16) ^ s_swz(m);

    // kt-permutation: slots 0,1 = this wave's OWN k-tiles (2w, 2w+1) -- the
    // hidden block this wave itself writes; slots 2..7 = the other 6.
    int rdoff[8];
    bf16x8 Ef[32];                       // E^T fragments, A-operand
    #pragma unroll
    for (int i = 0; i < 8; ++i) {
        int j = i - 2;
        int kt = (i < 2) ? (2 * w + i) : (j + ((j >= 2 * w) ? 2 : 0));
        rdoff[i] = rd_base + kt * 64;
        #pragma unroll
        for (int c = 0; c < 4; ++c)
            Ef[c * 8 + i] = *(const bf16x8*)(Et + (size_t)(w * 64 + c * 16 + m) * HID
                                             + quad * 8 + kt * 32);
    }

    // write offsets: 4 contiguous hidden cols at batch row m (one b64 each)
    int woff4[4];
    #pragma unroll
    for (int c = 0; c < 4; ++c)
        woff4[c] = ((m * SSTR + w * 64 + c * 16 + quad * 4) * 2) ^ s_swz(m);

    float a = alpha[0];
    int K = Kp[0];
    if (K < 1 || K > 64) K = 1;

    const bf16_t* wlo = wxp + (size_t)g * 4096 + (size_t)tid * 8;
    const bf16_t* whi = wlo + 2048;
    const long WSTR = 65536;   // elems per timestep (16 tiles * 4096)

    // per-lane h pointer: batch row m, hidden runs w*64+c*16+quad*4
    const float* hrow = h_in + (size_t)(g * 16 + m) * HID + w * 64 + quad * 4;
    float* orow = out + (size_t)(g * 16 + m) * HID + w * 64 + quad * 4;

    if (K == 1) {
        // K==1: hp==hc -> single scaled state Q = LAM*2*h (per lane: f32x4 per c).
        // pre_l = acc + Q;  u = rcp(exp2(pre_l)+1);  Q' = -2A*u + (B2*Q + A).
        const float A2 = 2.0f * a * LAM;
        const float B2 = 1.0f - 2.0f * a;
        const float NA2 = -2.0f * A2;

        f32x4 q4[4];
        #pragma unroll
        for (int c = 0; c < 4; ++c) {
            f32x4 hv = *(const f32x4*)(hrow + c * 16);
            f32x4 Q = hv * (2.0f * LAM);
            q4[c] = Q;
            bf16x4 v;
            #pragma unroll
            for (int r = 0; r < 4; ++r) v[r] = (bf16_t)Q[r];
            *(bf16x4*)((char*)&S[0][0] + woff4[c]) = v;
        }
        __syncthreads();

        // own k-tiles of the initial S -> registers
        bf16x8 af_own0 = *(const bf16x8*)((const char*)&S[0][0] + rdoff[0]);
        bf16x8 af_own1 = *(const bf16x8*)((const char*)&S[0][0] + rdoff[1]);

        // 2-deep wx prefetch: loads stay in flight across raw barriers
        bf16x8 wlA = *(const bf16x8*)(wlo);
        bf16x8 whA = *(const bf16x8*)(whi);
        bf16x8 wlB = *(const bf16x8*)(wlo + WSTR);
        bf16x8 whB = *(const bf16x8*)(whi + WSTR);

        auto step = [&](int p, int t) {   // p is a literal at both call sites
            int tpf = (t + 2 < SEQ) ? t + 2 : SEQ - 1;
            bf16x8 wlC = *(const bf16x8*)(wlo + (long)tpf * WSTR);
            bf16x8 whC = *(const bf16x8*)(whi + (long)tpf * WSTR);

            // issue the 6 OTHER-wave k-tile reads
            const char* sb = (const char*)&S[p][0];
            bf16x8 af2 = *(const bf16x8*)(sb + rdoff[2]);
            bf16x8 af3 = *(const bf16x8*)(sb + rdoff[3]);
            bf16x8 af4 = *(const bf16x8*)(sb + rdoff[4]);
            bf16x8 af5 = *(const bf16x8*)(sb + rdoff[5]);
            bf16x8 af6 = *(const bf16x8*)(sb + rdoff[6]);
            bf16x8 af7 = *(const bf16x8*)(sb + rdoff[7]);

            f32x4 acc[4], accb[4];
            #pragma unroll
            for (int r = 0; r < 4; ++r) {
                acc[0][r] = (float)wlA[r];
                acc[1][r] = (float)wlA[4 + r];
                acc[2][r] = (float)whA[r];
                acc[3][r] = (float)whA[4 + r];
            }
            #pragma unroll
            for (int c = 0; c < 4; ++c) accb[c] = (f32x4){0.f, 0.f, 0.f, 0.f};

            // own MFMAs first (fragments pre-read before the barrier)
            #pragma unroll
            for (int c = 0; c < 4; ++c)
                acc[c] = __builtin_amdgcn_mfma_f32_16x16x32_bf16(Ef[c * 8 + 0], af_own0, acc[c], 0, 0, 0);
            #pragma unroll
            for (int c = 0; c < 4; ++c)
                acc[c] = __builtin_amdgcn_mfma_f32_16x16x32_bf16(Ef[c * 8 + 1], af_own1, acc[c], 0, 0, 0);
            #pragma unroll
            for (int c = 0; c < 4; ++c)
                acc[c] = __builtin_amdgcn_mfma_f32_16x16x32_bf16(Ef[c * 8 + 2], af2, acc[c], 0, 0, 0);
            #pragma unroll
            for (int c = 0; c < 4; ++c)
                acc[c] = __builtin_amdgcn_mfma_f32_16x16x32_bf16(Ef[c * 8 + 3], af3, acc[c], 0, 0, 0);
            #pragma unroll
            for (int c = 0; c < 4; ++c)
                accb[c] = __builtin_amdgcn_mfma_f32_16x16x32_bf16(Ef[c * 8 + 4], af4, accb[c], 0, 0, 0);
            #pragma unroll
            for (int c = 0; c < 4; ++c)
                accb[c] = __builtin_amdgcn_mfma_f32_16x16x32_bf16(Ef[c * 8 + 5], af5, accb[c], 0, 0, 0);
            #pragma unroll
            for (int c = 0; c < 4; ++c)
                accb[c] = __builtin_amdgcn_mfma_f32_16x16x32_bf16(Ef[c * 8 + 6], af6, accb[c], 0, 0, 0);
            #pragma unroll
            for (int c = 0; c < 4; ++c)
                accb[c] = __builtin_amdgcn_mfma_f32_16x16x32_bf16(Ef[c * 8 + 7], af7, accb[c], 0, 0, 0);

            char* swp = (char*)&S[p ^ 1][0];
            #pragma unroll
            for (int c = 0; c < 4; ++c) {
                f32x4 pre = (acc[c] + accb[c]) + q4[c];
                f32x4 u;
                #pragma unroll
                for (int r = 0; r < 4; ++r) {
                    float e = __builtin_amdgcn_exp2f(pre[r]);
                    u[r] = __builtin_amdgcn_rcpf(e + 1.0f);
                }
                f32x4 qn = q4[c] * B2 + A2;     // pk_fma
                qn = u * NA2 + qn;               // pk_fma
                q4[c] = qn;
                bf16x4 v;
                #pragma unroll
                for (int r = 0; r < 4; ++r) v[r] = (bf16_t)qn[r];
                *(bf16x4*)(swp + woff4[c]) = v;  // one ds_write_b64
            }
            // drain LDS writes, pre-read OWN k-tiles of new S (no barrier needed
            // for own cols), then barrier
            asm volatile("s_waitcnt lgkmcnt(0)" ::: "memory");
            af_own0 = *(const bf16x8*)(swp + rdoff[0]);
            af_own1 = *(const bf16x8*)(swp + rdoff[1]);
            __builtin_amdgcn_s_barrier();
            __builtin_amdgcn_sched_barrier(0);
            wlA = wlB; whA = whB; wlB = wlC; whB = whC;
        };
        for (int t = 0; t < SEQ; t += 2) { step(0, t); step(1, t + 1); }

        const float OS = 0.5f / LAM;
        #pragma unroll
        for (int c = 0; c < 4; ++c) {
            f32x4 o = q4[c] * OS;
            *(f32x4*)(orow + c * 16) = o;
        }
    } else {
        // general K path (not exercised by the bench; kept correct).
        // wxp is LAM-scaled: acc = LAM*wx + LAM*(s@E)^T-part; sL = LAM*s.
        f32x4 hp4[4], hc4[4], sL4[4];
        #pragma unroll
        for (int c = 0; c < 4; ++c) {
            f32x4 hv = *(const f32x4*)(hrow + c * 16);
            hp4[c] = hv; hc4[c] = hv;
            f32x4 sl = hv * (2.0f * LAM);
            sL4[c] = sl;
            bf16x4 v;
            #pragma unroll
            for (int r = 0; r < 4; ++r) v[r] = (bf16_t)sl[r];
            *(bf16x4*)((char*)&S[0][0] + woff4[c]) = v;
        }
        float one_ma = 1.0f - a;
        __syncthreads();
        bf16x8 wl = *(const bf16x8*)(wlo);
        bf16x8 wh = *(const bf16x8*)(whi);
        int p = 0;
        for (int t = 0; t < SEQ; ++t) {
            int tn = (t + 1 < SEQ) ? t + 1 : t;
            bf16x8 wln = *(const bf16x8*)(wlo + (long)tn * WSTR);
            bf16x8 whn = *(const bf16x8*)(whi + (long)tn * WSTR);
            for (int k = 0; k < K; ++k) {
                f32x4 acc[4];
                #pragma unroll
                for (int r = 0; r < 4; ++r) {
                    acc[0][r] = (float)wl[r];
                    acc[1][r] = (float)wl[4 + r];
                    acc[2][r] = (float)wh[r];
                    acc[3][r] = (float)wh[4 + r];
                }
                const char* sb = (const char*)&S[p][0];
                #pragma unroll
                for (int i = 0; i < 8; ++i) {
                    bf16x8 bf = *(const bf16x8*)(sb + rdoff[i]);
                    #pragma unroll
                    for (int c = 0; c < 4; ++c)
                        acc[c] = __builtin_amdgcn_mfma_f32_16x16x32_bf16(Ef[c * 8 + i], bf, acc[c], 0, 0, 0);
                }
                bool last = (k == K - 1);
                char* swp = (char*)&S[p ^ 1][0];
                #pragma unroll
                for (int c = 0; c < 4; ++c) {
                    bf16x4 v;
                    #pragma unroll
                    for (int r = 0; r < 4; ++r) {
                        float pre_l = acc[c][r] + sL4[c][r];
                        float T = fast_tanh_scaled(pre_l);
                        float hn = a * (T - hp4[c][r]) + one_ma * hc4[c][r];
                        float sn;
                        if (last) { hp4[c][r] = hn; hc4[c][r] = hn; sn = 2.0f * hn; }
                        else      { hc4[c][r] = hn; sn = hn + hp4[c][r]; }
                        sL4[c][r] = LAM * sn;
                        v[r] = (bf16_t)(LAM * sn);
                    }
                    *(bf16x4*)(swp + woff4[c]) = v;
                }
                p ^= 1;
                __syncthreads();
            }
            wl = wln; wh = whn;
        }
        #pragma unroll
        for (int c = 0; c < 4; ++c)
            *(f32x4*)(orow + c * 16) = hp4[c];
    }
}

// ---------- fallback: fused scan (16 WGs x 256 threads), wxp workspace unavailable ----------
// (old proven non-transposed structure; self-consistent, does not use wxp)
__global__ __launch_bounds__(256, 1) void k_scan_fused(const float* __restrict__ h_in,
                                                 const float* __restrict__ alpha,
                                                 const int* __restrict__ Kp,
                                                 const bf16_t* __restrict__ Et,
                                                 const bf16_t* __restrict__ WPt,
                                                 const float* __restrict__ bP,
                                                 const float* __restrict__ x,
                                                 float* __restrict__ out) {
    __shared__ bf16_t S[2][16 * SSTR];
    int g = blockIdx.x;
    int tid = threadIdx.x;
    int lane = tid & 63, w = tid >> 6, quad = lane >> 4, m = lane & 15;
    int colbase = w * 64 + m;
    bf16x8 Ef[32];
    bf16x8 Wf[16];
    float bPv[4];
    #pragma unroll
    for (int c = 0; c < 4; ++c) {
        int col = colbase + c * 16;
        bPv[c] = bP[col];
        const bf16_t* ep = Et + (size_t)col * HID + quad * 8;
        #pragma unroll
        for (int kt = 0; kt < 8; ++kt)
            Ef[c * 8 + kt] = *(const bf16x8*)(ep + kt * 32);
        const bf16_t* wpp = WPt + (size_t)col * NF + quad * 8;
        #pragma unroll
        for (int kt = 0; kt < 4; ++kt)
            Wf[c * 4 + kt] = *(const bf16x8*)(wpp + kt * 32);
    }
    float hp[16], hc[16], sreg[16];
    int woff[16];
    #pragma unroll
    for (int c = 0; c < 4; ++c)
        #pragma unroll
        for (int r = 0; r < 4; ++r) {
            int e = c * 4 + r;
            int row = quad * 4 + r, col = colbase + c * 16;
            woff[e] = ((row * SSTR + col) * 2) ^ s_swz(row);
            float v = h_in[(g * 16 + row) * HID + col];
            hp[e] = v; hc[e] = v; sreg[e] = 2.0f * v;
            *(bf16_t*)((char*)&S[0][0] + woff[e]) = (bf16_t)(2.0f * v);
        }
    const int rd_base = (m * (SSTR * 2) + quad * 16) ^ s_swz(m);
    float a = alpha[0];
    float one_ma = 1.0f - a;
    int K = Kp[0];
    if (K < 1 || K > 64) K = 1;
    __syncthreads();
    const float* xrow = x + ((g * 16 + m) * NF + quad * 8);
    bf16x8 xf[4];
    #pragma unroll
    for (int kt = 0; kt < 4; ++kt) {
        f32x4 xa = *(const f32x4*)(xrow + kt * 32);
        f32x4 xb = *(const f32x4*)(xrow + kt * 32 + 4);
        bf16x8 f;
        #pragma unroll
        for (int j = 0; j < 4; ++j) { f[j] = (bf16_t)xa[j]; f[4 + j] = (bf16_t)xb[j]; }
        xf[kt] = f;
    }
    int p = 0;
    for (int t = 0; t < SEQ; ++t) {
        int tn = (t + 1 < SEQ) ? t + 1 : t;
        const float* xn = xrow + (size_t)tn * (256 * NF);
        bf16x8 xnf[4];
        #pragma unroll
        for (int kt = 0; kt < 4; ++kt) {
            f32x4 xa = *(const f32x4*)(xn + kt * 32);
            f32x4 xb = *(const f32x4*)(xn + kt * 32 + 4);
            bf16x8 f;
            #pragma unroll
            for (int j = 0; j < 4; ++j) { f[j] = (bf16_t)xa[j]; f[4 + j] = (bf16_t)xb[j]; }
            xnf[kt] = f;
        }
        f32x4 wxacc[4];
        #pragma unroll
        for (int c = 0; c < 4; ++c) wxacc[c] = (f32x4){bPv[c], bPv[c], bPv[c], bPv[c]};
        #pragma unroll
        for (int kt = 0; kt < 4; ++kt)
            #pragma unroll
            for (int c = 0; c < 4; ++c)
                wxacc[c] = __builtin_amdgcn_mfma_f32_16x16x32_bf16(xf[kt], Wf[c * 4 + kt], wxacc[c], 0, 0, 0);
        for (int k = 0; k < K; ++k) {
            f32x4 acc[4];
            #pragma unroll
            for (int c = 0; c < 4; ++c) acc[c] = wxacc[c];
            const char* sb = (const char*)&S[p][0];
            #pragma unroll
            for (int kt = 0; kt < 8; ++kt) {
                bf16x8 af = *(const bf16x8*)(sb + rd_base + kt * 64);
                #pragma unroll
                for (int c = 0; c < 4; ++c)
                    acc[c] = __builtin_amdgcn_mfma_f32_16x16x32_bf16(af, Ef[c * 8 + kt], acc[c], 0, 0, 0);
            }
            bool last = (k == K - 1);
            char* swp = (char*)&S[p ^ 1][0];
            #pragma unroll
            for (int c = 0; c < 4; ++c) {
                #pragma unroll
                for (int r = 0; r < 4; ++r) {
                    int e = c * 4 + r;
                    float pre = acc[c][r] + sreg[e];
                    float T = fast_tanh_scaled(LAM * pre);
                    float hn = a * (T - hp[e]) + one_ma * hc[e];
                    float sn;
                    if (last) { hp[e] = hn; hc[e] = hn; sn = 2.0f * hn; }
                    else      { hc[e] = hn; sn = hn + hp[e]; }
                    sreg[e] = sn;
                    *(bf16_t*)(swp + woff[e]) = (bf16_t)sn;
                }
            }
            p ^= 1;
            __syncthreads();
        }
        #pragma unroll
        for (int kt = 0; kt < 4; ++kt) xf[kt] = xnf[kt];
    }
    #pragma unroll
    for (int c = 0; c < 4; ++c)
        #pragma unroll
        for (int r = 0; r < 4; ++r) {
            int row = quad * 4 + r, col = colbase + c * 16;
            out[(g * 16 + row) * HID + col] = hp[c * 4 + r];
        }
}

extern "C" void kernel_launch(void* const* d_in, const int* in_sizes, int n_in,
                              void* d_out, int out_size, void* d_ws, size_t ws_size,
                              hipStream_t stream) {
    const float* x     = (const float*)d_in[0];
    const float* h     = (const float*)d_in[1];
    const float* W     = (const float*)d_in[2];
    const float* b     = (const float*)d_in[3];
    const float* V     = (const float*)d_in[4];
    const float* V2    = (const float*)d_in[5];
    const float* alpha = (const float*)d_in[6];
    const int*   Kp    = (const int*)d_in[7];

    char* ws = (char*)d_ws;
    float*  P   = (float*)ws;                     // 256 KB
    bf16_t* Et  = (bf16_t*)(ws + (256u << 10));   // 128 KB (E^T)
    bf16_t* WPt = (bf16_t*)(ws + (384u << 10));   // 64 KB ((W@P)^T)
    float*  bP  = (float*)(ws + (448u << 10));    // 1 KB
    bf16_t* wxp = (bf16_t*)(ws + (512u << 10));   // 128 MB (optional)
    size_t need = (512u << 10) + (size_t)SEQ * 16 * 512 * 8 * sizeof(bf16_t);

    hipLaunchKernelGGL(k_P,  dim3(256), dim3(256), 0, stream, V2, V, P);
    hipLaunchKernelGGL(k_E,  dim3(256), dim3(256), 0, stream, P, Et);
    hipLaunchKernelGGL(k_WP, dim3(129), dim3(256), 0, stream, W, b, P, WPt, bP);
    if (ws_size >= need) {
        hipLaunchKernelGGL(k_wxp, dim3(2048), dim3(256), 0, stream, x, WPt, bP, wxp);
        hipLaunchKernelGGL(k_scan_pre, dim3(16), dim3(256), 0, stream, h, alpha, Kp, Et, wxp, (float*)d_out);
    } else {
        hipLaunchKernelGGL(k_scan_fused, dim3(16), dim3(256), 0, stream, h, alpha, Kp, Et, WPt, bP, x, (float*)d_out);
    }
}